// Round 1
// 5905.261 us; speedup vs baseline: 1.8779x; 1.8779x over previous
//
#include <hip/hip_runtime.h>
#include <math.h>

#define B 512
#define S 64
#define T 32
#define E 512
#define H 1024
#define VOUTD 128
#define H2 (2*H)
#define H3 (3*H)
#define H6 (6*H)

typedef unsigned short ushortT;
typedef unsigned int uintT;
typedef __attribute__((ext_vector_type(8))) short short8;
typedef __attribute__((ext_vector_type(4))) float floatx4;

__device__ __forceinline__ float sigmoidf_(float x) { return 1.0f / (1.0f + expf(-x)); }

// ===========================================================================
// Split fp32 -> bf16 hi/lo planes. hi = trunc16(x), lo = trunc16(x - hi).
// ===========================================================================
__global__ __launch_bounds__(256) void split_bf16(
    const float4* __restrict__ x, uint2* __restrict__ hi, uint2* __restrict__ lo, int n4)
{
    int i = blockIdx.x * 256 + threadIdx.x;
    if (i >= n4) return;
    float4 v = x[i];
    uintT ux = __float_as_uint(v.x), uy = __float_as_uint(v.y);
    uintT uz = __float_as_uint(v.z), uw = __float_as_uint(v.w);
    uintT lx = __float_as_uint(v.x - __uint_as_float(ux & 0xFFFF0000u)) >> 16;
    uintT ly = __float_as_uint(v.y - __uint_as_float(uy & 0xFFFF0000u)) >> 16;
    uintT lz = __float_as_uint(v.z - __uint_as_float(uz & 0xFFFF0000u)) >> 16;
    uintT lw = __float_as_uint(v.w - __uint_as_float(uw & 0xFFFF0000u)) >> 16;
    hi[i] = make_uint2((ux >> 16) | (uy & 0xFFFF0000u), (uz >> 16) | (uw & 0xFFFF0000u));
    lo[i] = make_uint2(lx | (ly << 16), lz | (lw << 16));
}

__global__ __launch_bounds__(256) void zero16(uint4* __restrict__ p, int n)
{
    int i = blockIdx.x * 256 + threadIdx.x;
    if (i < n) p[i] = make_uint4(0u, 0u, 0u, 0u);
}

// ===========================================================================
// FUSED recurrent step (encoder): gh = h @ W_hh^T computed full-K per block,
// gate applied in the epilogue, h fp32 + bf16 planes written directly.
// Tile: 64 rows x (3 gates x 32 j). 4 waves (2x2): wave = 32 rows x
// (3 gates x 16 j). Gates r/z/n for one (row,j) land in the SAME lane/reg
// (C layout col=lane&15, row=(lane>>4)*4+reg) -> gate is pure per-lane ALU.
// 3-term split-bf16 MFMA (Ah*Bh + Ah*Bl + Al*Bh), fp32 accum, same numerics
// as the previous split path. Grid = 512 blocks, XCD-swizzled so all 16
// M-blocks of a j-group share one XCD's L2 (W slice 1.5MB/XCD stays hot).
// h planes ping-pong (in != out) since every block reads the full In planes.
// ===========================================================================
__global__ __launch_bounds__(256) void fused_step_enc(
    const ushortT* __restrict__ Ahi, const ushortT* __restrict__ Alo,   // in planes [2B][H]
    const ushortT* __restrict__ Whi_f, const ushortT* __restrict__ Wlo_f,
    const ushortT* __restrict__ Whi_b, const ushortT* __restrict__ Wlo_b,
    const float* __restrict__ giTabF, const float* __restrict__ giTabB,
    const int* __restrict__ src, int s,
    const float* __restrict__ bhF, const float* __restrict__ bhB,
    float* __restrict__ h,                                              // fp32 [2B][H]
    ushortT* __restrict__ hiOut, ushortT* __restrict__ loOut)           // out planes
{
    __shared__ ushortT sAh[2][64 * 32], sAl[2][64 * 32];
    __shared__ ushortT sBh[2][96 * 32], sBl[2][96 * 32];
    __shared__ int sTok[64];

    const int t    = threadIdx.x;
    const int lane = t & 63;
    const int w    = t >> 6;

    // XCD-aware decode: 512 blocks -> (jg in [0,32), mb in [0,16)), all mb of
    // a jg on one XCD (assumes round-robin bid->XCD; perf-only heuristic).
    const int bid = blockIdx.x;
    const int xcd = bid & 7;
    const int q   = bid >> 3;
    const int jg  = xcd + 8 * (q & 3);
    const int mb  = q >> 2;
    const int j0  = jg * 32;
    const int m0  = mb * 64;
    const bool bwd = (m0 >= B);

    const ushortT* Whi   = bwd ? Whi_b : Whi_f;
    const ushortT* Wlo   = bwd ? Wlo_b : Wlo_f;
    const float*   giTab = bwd ? giTabB : giTabF;
    const float*   bh    = bwd ? bhB : bhF;

    if (t < 64) {
        int b = (m0 + t) & (B - 1);
        sTok[t] = src[b * S + (bwd ? (S - 1 - s) : s)];
    }

    // staging: A chunk c=t: row=t>>2 (64 rows), kseg=(t&3)*8.
    //          B chunk c0=t (rows 0..63), c1=256+t for t<128 (rows 64..95).
    //          LDS B row brow holds W row (brow>>5)*H + j0 + (brow&31).
    const int kseg = (t & 3) * 8;
    const ushortT* gAh = Ahi + (size_t)(m0 + (t >> 2)) * H + kseg;
    const ushortT* gAl = Alo + (size_t)(m0 + (t >> 2)) * H + kseg;
    const int brow0 = t >> 2;
    const int wr0   = (brow0 >> 5) * H + j0 + (brow0 & 31);
    const ushortT* gBh0 = Whi + (size_t)wr0 * H + kseg;
    const ushortT* gBl0 = Wlo + (size_t)wr0 * H + kseg;
    const int brow1 = 64 + (t >> 2);
    const int wr1   = (brow1 >> 5) * H + j0 + (brow1 & 31);
    const ushortT* gBh1 = Whi + (size_t)wr1 * H + kseg;
    const ushortT* gBl1 = Wlo + (size_t)wr1 * H + kseg;
    const int ldsA  = t * 8;
    const int ldsB0 = t * 8;
    const int ldsB1 = (256 + t) * 8;
    const bool doB1 = (t < 128);   // waves 0,1 only -> wave-uniform

    const int koff = (lane >> 4) * 8;
    const int rA0  = (w >> 1) * 32 + (lane & 15);
    const int rB0  = (w & 1) * 16 + (lane & 15);

    floatx4 acc[2][3];
#pragma unroll
    for (int mi = 0; mi < 2; ++mi)
#pragma unroll
        for (int g = 0; g < 3; ++g) acc[mi][g] = (floatx4){0.f, 0.f, 0.f, 0.f};

    uint4 vAh, vAl, vBh0, vBl0, vBh1 = {}, vBl1 = {};
    vAh  = *(const uint4*)gAh;  vAl  = *(const uint4*)gAl;
    vBh0 = *(const uint4*)gBh0; vBl0 = *(const uint4*)gBl0;
    if (doB1) { vBh1 = *(const uint4*)gBh1; vBl1 = *(const uint4*)gBl1; }
    *(uint4*)&sAh[0][ldsA]  = vAh;  *(uint4*)&sAl[0][ldsA]  = vAl;
    *(uint4*)&sBh[0][ldsB0] = vBh0; *(uint4*)&sBl[0][ldsB0] = vBl0;
    if (doB1) { *(uint4*)&sBh[0][ldsB1] = vBh1; *(uint4*)&sBl[0][ldsB1] = vBl1; }
    __syncthreads();

    int p = 0;
    const int nCh = H / 32;
    for (int ck = 0; ck < nCh; ++ck) {
        const bool hasNext = (ck + 1 < nCh);
        if (hasNext) {
            const int k0 = (ck + 1) * 32;
            vAh  = *(const uint4*)(gAh + k0);  vAl  = *(const uint4*)(gAl + k0);
            vBh0 = *(const uint4*)(gBh0 + k0); vBl0 = *(const uint4*)(gBl0 + k0);
            if (doB1) { vBh1 = *(const uint4*)(gBh1 + k0); vBl1 = *(const uint4*)(gBl1 + k0); }
        }
        short8 fah[2], fal[2], fbh[3], fbl[3];
#pragma unroll
        for (int mi = 0; mi < 2; ++mi) {
            fah[mi] = *(const short8*)&sAh[p][(rA0 + mi * 16) * 32 + koff];
            fal[mi] = *(const short8*)&sAl[p][(rA0 + mi * 16) * 32 + koff];
        }
#pragma unroll
        for (int g = 0; g < 3; ++g) {
            fbh[g] = *(const short8*)&sBh[p][(rB0 + g * 32) * 32 + koff];
            fbl[g] = *(const short8*)&sBl[p][(rB0 + g * 32) * 32 + koff];
        }
#pragma unroll
        for (int mi = 0; mi < 2; ++mi)
#pragma unroll
            for (int g = 0; g < 3; ++g) {
                acc[mi][g] = __builtin_amdgcn_mfma_f32_16x16x32_bf16(fah[mi], fbh[g], acc[mi][g], 0, 0, 0);
                acc[mi][g] = __builtin_amdgcn_mfma_f32_16x16x32_bf16(fah[mi], fbl[g], acc[mi][g], 0, 0, 0);
                acc[mi][g] = __builtin_amdgcn_mfma_f32_16x16x32_bf16(fal[mi], fbh[g], acc[mi][g], 0, 0, 0);
            }
        if (hasNext) {
            __syncthreads();
            const int pq = p ^ 1;
            *(uint4*)&sAh[pq][ldsA]  = vAh;  *(uint4*)&sAl[pq][ldsA]  = vAl;
            *(uint4*)&sBh[pq][ldsB0] = vBh0; *(uint4*)&sBl[pq][ldsB0] = vBl0;
            if (doB1) { *(uint4*)&sBh[pq][ldsB1] = vBh1; *(uint4*)&sBl[pq][ldsB1] = vBl1; }
            __syncthreads();
            p = pq;
        }
    }

    // fused gate epilogue: r/z/n for (row,colj) are in-lane.
    const int colj = j0 + (w & 1) * 16 + (lane & 15);
    const float bR = bh[colj], bZ = bh[H + colj], bN = bh[2 * H + colj];
    const int rloc0 = (w >> 1) * 32 + (lane >> 4) * 4;
#pragma unroll
    for (int mi = 0; mi < 2; ++mi) {
#pragma unroll
        for (int r = 0; r < 4; ++r) {
            const int rloc = rloc0 + mi * 16 + r;
            const int row  = m0 + rloc;
            const float* gi = giTab + (size_t)sTok[rloc] * H3;
            float ghr = acc[mi][0][r] + bR;
            float ghz = acc[mi][1][r] + bZ;
            float ghn = acc[mi][2][r] + bN;
            float rr = sigmoidf_(gi[colj] + ghr);
            float z  = sigmoidf_(gi[H + colj] + ghz);
            float n  = tanhf(gi[2 * H + colj] + rr * ghn);
            const size_t idx = (size_t)row * H + colj;
            float hnew = (1.0f - z) * n + z * h[idx];
            h[idx] = hnew;
            uintT u = __float_as_uint(hnew);
            hiOut[idx] = (ushortT)(u >> 16);
            loOut[idx] = (ushortT)(__float_as_uint(hnew - __uint_as_float(u & 0xFFFF0000u)) >> 16);
        }
    }
}

// ===========================================================================
// FUSED recurrent step (decoder): Hd = 2H, gates at {j, 2H+j, 4H+j} of the
// 6H W_hh_d rows. Same structure; tok gathered from tok[] (prev argmax).
// Grid = (B/64) x (2H/32) = 8 x 64 = 512 blocks.
// ===========================================================================
__global__ __launch_bounds__(256) void fused_step_dec(
    const ushortT* __restrict__ Ahi, const ushortT* __restrict__ Alo,   // in planes [B][2H]
    const ushortT* __restrict__ Whi, const ushortT* __restrict__ Wlo,   // [6H][2H]
    const float* __restrict__ giTabD, const int* __restrict__ tok,
    const float* __restrict__ bhD,
    float* __restrict__ h,                                              // fp32 [B][2H]
    ushortT* __restrict__ hiOut, ushortT* __restrict__ loOut)
{
    __shared__ ushortT sAh[2][64 * 32], sAl[2][64 * 32];
    __shared__ ushortT sBh[2][96 * 32], sBl[2][96 * 32];
    __shared__ int sTok[64];

    const int t    = threadIdx.x;
    const int lane = t & 63;
    const int w    = t >> 6;

    const int bid = blockIdx.x;
    const int xcd = bid & 7;
    const int q   = bid >> 3;
    const int jg  = xcd + 8 * (q & 7);   // [0,64)
    const int mb  = q >> 3;              // [0,8)
    const int j0  = jg * 32;
    const int m0  = mb * 64;

    if (t < 64) sTok[t] = tok[m0 + t];

    const int kseg = (t & 3) * 8;
    const ushortT* gAh = Ahi + (size_t)(m0 + (t >> 2)) * H2 + kseg;
    const ushortT* gAl = Alo + (size_t)(m0 + (t >> 2)) * H2 + kseg;
    const int brow0 = t >> 2;
    const int wr0   = (brow0 >> 5) * H2 + j0 + (brow0 & 31);
    const ushortT* gBh0 = Whi + (size_t)wr0 * H2 + kseg;
    const ushortT* gBl0 = Wlo + (size_t)wr0 * H2 + kseg;
    const int brow1 = 64 + (t >> 2);
    const int wr1   = (brow1 >> 5) * H2 + j0 + (brow1 & 31);
    const ushortT* gBh1 = Whi + (size_t)wr1 * H2 + kseg;
    const ushortT* gBl1 = Wlo + (size_t)wr1 * H2 + kseg;
    const int ldsA  = t * 8;
    const int ldsB0 = t * 8;
    const int ldsB1 = (256 + t) * 8;
    const bool doB1 = (t < 128);

    const int koff = (lane >> 4) * 8;
    const int rA0  = (w >> 1) * 32 + (lane & 15);
    const int rB0  = (w & 1) * 16 + (lane & 15);

    floatx4 acc[2][3];
#pragma unroll
    for (int mi = 0; mi < 2; ++mi)
#pragma unroll
        for (int g = 0; g < 3; ++g) acc[mi][g] = (floatx4){0.f, 0.f, 0.f, 0.f};

    uint4 vAh, vAl, vBh0, vBl0, vBh1 = {}, vBl1 = {};
    vAh  = *(const uint4*)gAh;  vAl  = *(const uint4*)gAl;
    vBh0 = *(const uint4*)gBh0; vBl0 = *(const uint4*)gBl0;
    if (doB1) { vBh1 = *(const uint4*)gBh1; vBl1 = *(const uint4*)gBl1; }
    *(uint4*)&sAh[0][ldsA]  = vAh;  *(uint4*)&sAl[0][ldsA]  = vAl;
    *(uint4*)&sBh[0][ldsB0] = vBh0; *(uint4*)&sBl[0][ldsB0] = vBl0;
    if (doB1) { *(uint4*)&sBh[0][ldsB1] = vBh1; *(uint4*)&sBl[0][ldsB1] = vBl1; }
    __syncthreads();

    int p = 0;
    const int nCh = H2 / 32;
    for (int ck = 0; ck < nCh; ++ck) {
        const bool hasNext = (ck + 1 < nCh);
        if (hasNext) {
            const int k0 = (ck + 1) * 32;
            vAh  = *(const uint4*)(gAh + k0);  vAl  = *(const uint4*)(gAl + k0);
            vBh0 = *(const uint4*)(gBh0 + k0); vBl0 = *(const uint4*)(gBl0 + k0);
            if (doB1) { vBh1 = *(const uint4*)(gBh1 + k0); vBl1 = *(const uint4*)(gBl1 + k0); }
        }
        short8 fah[2], fal[2], fbh[3], fbl[3];
#pragma unroll
        for (int mi = 0; mi < 2; ++mi) {
            fah[mi] = *(const short8*)&sAh[p][(rA0 + mi * 16) * 32 + koff];
            fal[mi] = *(const short8*)&sAl[p][(rA0 + mi * 16) * 32 + koff];
        }
#pragma unroll
        for (int g = 0; g < 3; ++g) {
            fbh[g] = *(const short8*)&sBh[p][(rB0 + g * 32) * 32 + koff];
            fbl[g] = *(const short8*)&sBl[p][(rB0 + g * 32) * 32 + koff];
        }
#pragma unroll
        for (int mi = 0; mi < 2; ++mi)
#pragma unroll
            for (int g = 0; g < 3; ++g) {
                acc[mi][g] = __builtin_amdgcn_mfma_f32_16x16x32_bf16(fah[mi], fbh[g], acc[mi][g], 0, 0, 0);
                acc[mi][g] = __builtin_amdgcn_mfma_f32_16x16x32_bf16(fah[mi], fbl[g], acc[mi][g], 0, 0, 0);
                acc[mi][g] = __builtin_amdgcn_mfma_f32_16x16x32_bf16(fal[mi], fbh[g], acc[mi][g], 0, 0, 0);
            }
        if (hasNext) {
            __syncthreads();
            const int pq = p ^ 1;
            *(uint4*)&sAh[pq][ldsA]  = vAh;  *(uint4*)&sAl[pq][ldsA]  = vAl;
            *(uint4*)&sBh[pq][ldsB0] = vBh0; *(uint4*)&sBl[pq][ldsB0] = vBl0;
            if (doB1) { *(uint4*)&sBh[pq][ldsB1] = vBh1; *(uint4*)&sBl[pq][ldsB1] = vBl1; }
            __syncthreads();
            p = pq;
        }
    }

    const int colj = j0 + (w & 1) * 16 + (lane & 15);
    const float bR = bhD[colj], bZ = bhD[H2 + colj], bN = bhD[2 * H2 + colj];
    const int rloc0 = (w >> 1) * 32 + (lane >> 4) * 4;
#pragma unroll
    for (int mi = 0; mi < 2; ++mi) {
#pragma unroll
        for (int r = 0; r < 4; ++r) {
            const int rloc = rloc0 + mi * 16 + r;
            const int row  = m0 + rloc;
            const float* gi = giTabD + (size_t)sTok[rloc] * H6;
            float ghr = acc[mi][0][r] + bR;
            float ghz = acc[mi][1][r] + bZ;
            float ghn = acc[mi][2][r] + bN;
            float rr = sigmoidf_(gi[colj] + ghr);
            float z  = sigmoidf_(gi[H2 + colj] + ghz);
            float n  = tanhf(gi[2 * H2 + colj] + rr * ghn);
            const size_t idx = (size_t)row * H2 + colj;
            float hnew = (1.0f - z) * n + z * h[idx];
            h[idx] = hnew;
            uintT u = __float_as_uint(hnew);
            hiOut[idx] = (ushortT)(u >> 16);
            loOut[idx] = (ushortT)(__float_as_uint(hnew - __uint_as_float(u & 0xFFFF0000u)) >> 16);
        }
    }
}

// hh[b,0:H]=h_f[b], hh[b,H:2H]=h_b[b] (+ bf16 planes); tok[b]=tgt[b,0]
__global__ __launch_bounds__(256) void init_hh_tok_split(
    const float* __restrict__ h_f, const float* __restrict__ h_b,
    const int* __restrict__ tgt, float* __restrict__ hh,
    ushortT* __restrict__ hh_hi, ushortT* __restrict__ hh_lo, int* __restrict__ tok)
{
    int i = blockIdx.x * blockDim.x + threadIdx.x;   // over B*2H
    int b = i >> 11;
    int j = i & 2047;
    float v = (j < H) ? h_f[(size_t)b * H + j] : h_b[(size_t)b * H + (j - H)];
    hh[i] = v;
    uintT u = __float_as_uint(v);
    hh_hi[i] = (ushortT)(u >> 16);
    hh_lo[i] = (ushortT)(__float_as_uint(v - __uint_as_float(u & 0xFFFF0000u)) >> 16);
    if (j == 0) tok[b] = tgt[b * T];
}

// ===========================================================================
// logits = hh @ W_fc^T + b_fc (V=128); out[b,t,:]; tok[b]=argmax (first-idx ties)
// ===========================================================================
__global__ __launch_bounds__(128) void logits_argmax(
    const float* __restrict__ hh, const float* __restrict__ W_fc,
    const float* __restrict__ b_fc, float* __restrict__ out,
    int* __restrict__ tok, int t)
{
    __shared__ float sh[H2];
    __shared__ float svals[128];
    __shared__ int   sidx[128];
    const int b = blockIdx.x;
    const int v = threadIdx.x;
    const float* hrow = hh + (size_t)b * H2;
    for (int i = v; i < H2 / 4; i += 128)
        ((float4*)sh)[i] = ((const float4*)hrow)[i];
    __syncthreads();
    const float* wrow = W_fc + (size_t)v * H2;
    float acc = b_fc[v];
    for (int k = 0; k < H2; k += 4) {
        float4 w4 = *(const float4*)(wrow + k);
        float4 h4 = *(const float4*)(sh + k);
        acc += w4.x * h4.x + w4.y * h4.y + w4.z * h4.z + w4.w * h4.w;
    }
    out[(size_t)b * ((T - 1) * VOUTD) + (size_t)t * VOUTD + v] = acc;

    svals[v] = acc; sidx[v] = v;
    __syncthreads();
    for (int off = 64; off > 0; off >>= 1) {
        if (v < off) {
            float ov = svals[v + off]; int oi = sidx[v + off];
            if (ov > svals[v] || (ov == svals[v] && oi < sidx[v])) {
                svals[v] = ov; sidx[v] = oi;
            }
        }
        __syncthreads();
    }
    if (v == 0) tok[b] = sidx[0];
}

// ===========================================================================
// fp32 vector GEMM (R1-proven): C[M,N] = A @ W^T + bias. Used for the tiny
// gi-table precomputes (exact fp32) and as full fallback path.
// ===========================================================================
__global__ __launch_bounds__(256) void gemm_bias(
    const float* __restrict__ Abase,
    const int* __restrict__ idx, int idxStride, int idxOff, int lda,
    const float* __restrict__ W, const float* __restrict__ bias,
    float* __restrict__ C, int N, int K)
{
    __shared__ float As[16][68];
    __shared__ float Ws[16][68];
    const int t = threadIdx.x;
    const int m0 = blockIdx.y * 64, n0 = blockIdx.x * 64;
    const int lr = t >> 2, lc = (t & 3) << 2;
    const int tx = t & 15, ty = t >> 4;
    const int tn0 = tx << 2, tm0 = ty << 2;
    const int arow = m0 + lr;
    const float* Aptr = idx ? (Abase + (size_t)idx[arow * idxStride + idxOff] * lda)
                            : (Abase + (size_t)arow * lda);
    const float* Wptr = W + (size_t)(n0 + lr) * K;
    float acc[4][4] = {{0.f}};
    for (int k0 = 0; k0 < K; k0 += 16) {
        float4 a4 = *(const float4*)(Aptr + k0 + lc);
        float4 w4 = *(const float4*)(Wptr + k0 + lc);
        __syncthreads();
        As[lc+0][lr] = a4.x; As[lc+1][lr] = a4.y; As[lc+2][lr] = a4.z; As[lc+3][lr] = a4.w;
        Ws[lc+0][lr] = w4.x; Ws[lc+1][lr] = w4.y; Ws[lc+2][lr] = w4.z; Ws[lc+3][lr] = w4.w;
        __syncthreads();
#pragma unroll
        for (int kk = 0; kk < 16; ++kk) {
            float4 av = *(const float4*)&As[kk][tm0];
            float4 wv = *(const float4*)&Ws[kk][tn0];
            float am[4] = {av.x, av.y, av.z, av.w};
            float wn[4] = {wv.x, wv.y, wv.z, wv.w};
#pragma unroll
            for (int i = 0; i < 4; ++i)
#pragma unroll
                for (int j = 0; j < 4; ++j) acc[i][j] += am[i] * wn[j];
        }
    }
    const float b0 = bias[n0+tn0], b1 = bias[n0+tn0+1], b2 = bias[n0+tn0+2], b3 = bias[n0+tn0+3];
#pragma unroll
    for (int i = 0; i < 4; ++i) {
        float4 o = make_float4(acc[i][0]+b0, acc[i][1]+b1, acc[i][2]+b2, acc[i][3]+b3);
        *(float4*)(C + (size_t)(m0 + tm0 + i) * N + n0 + tn0) = o;
    }
}

__global__ __launch_bounds__(256) void gemm_enc(
    const float* __restrict__ Abase, int lda, int K,
    const int* __restrict__ srcIdx, int s,
    const float* __restrict__ W1, const float* __restrict__ bias1,
    const float* __restrict__ W2, const float* __restrict__ bias2,
    float* __restrict__ C, int N)
{
    __shared__ float As[16][68];
    __shared__ float Ws[16][68];
    const int t = threadIdx.x;
    const int m0 = blockIdx.y * 64, n0 = blockIdx.x * 64;
    const bool bwd = (m0 >= B);
    const float* W = bwd ? W2 : W1;
    const float* bias = bwd ? bias2 : bias1;
    const int lr = t >> 2, lc = (t & 3) << 2;
    const int tx = t & 15, ty = t >> 4;
    const int tn0 = tx << 2, tm0 = ty << 2;
    const int arow = m0 + lr;
    const float* Aptr;
    if (srcIdx) {
        int r = arow & (B - 1);
        int sidx = bwd ? (S - 1 - s) : s;
        Aptr = Abase + (size_t)srcIdx[r * S + sidx] * lda;
    } else Aptr = Abase + (size_t)arow * lda;
    const float* Wptr = W + (size_t)(n0 + lr) * K;
    float acc[4][4] = {{0.f}};
    for (int k0 = 0; k0 < K; k0 += 16) {
        float4 a4 = *(const float4*)(Aptr + k0 + lc);
        float4 w4 = *(const float4*)(Wptr + k0 + lc);
        __syncthreads();
        As[lc+0][lr] = a4.x; As[lc+1][lr] = a4.y; As[lc+2][lr] = a4.z; As[lc+3][lr] = a4.w;
        Ws[lc+0][lr] = w4.x; Ws[lc+1][lr] = w4.y; Ws[lc+2][lr] = w4.z; Ws[lc+3][lr] = w4.w;
        __syncthreads();
#pragma unroll
        for (int kk = 0; kk < 16; ++kk) {
            float4 av = *(const float4*)&As[kk][tm0];
            float4 wv = *(const float4*)&Ws[kk][tn0];
            float am[4] = {av.x, av.y, av.z, av.w};
            float wn[4] = {wv.x, wv.y, wv.z, wv.w};
#pragma unroll
            for (int i = 0; i < 4; ++i)
#pragma unroll
                for (int j = 0; j < 4; ++j) acc[i][j] += am[i] * wn[j];
        }
    }
    const float b0 = bias[n0+tn0], b1 = bias[n0+tn0+1], b2 = bias[n0+tn0+2], b3 = bias[n0+tn0+3];
#pragma unroll
    for (int i = 0; i < 4; ++i) {
        float4 o = make_float4(acc[i][0]+b0, acc[i][1]+b1, acc[i][2]+b2, acc[i][3]+b3);
        *(float4*)(C + (size_t)(m0 + tm0 + i) * N + n0 + tn0) = o;
    }
}

__global__ __launch_bounds__(256) void gru_gate(
    const float* __restrict__ gi, const float* __restrict__ gh,
    float* __restrict__ h, int Hd)
{
    int i = blockIdx.x * blockDim.x + threadIdx.x;
    int b = i / Hd, j = i - b * Hd;
    const float* gib = gi + (size_t)b * 3 * Hd;
    const float* ghb = gh + (size_t)b * 3 * Hd;
    float r = sigmoidf_(gib[j] + ghb[j]);
    float z = sigmoidf_(gib[Hd + j] + ghb[Hd + j]);
    float n = tanhf(gib[2 * Hd + j] + r * ghb[2 * Hd + j]);
    h[i] = (1.0f - z) * n + z * h[i];
}

__global__ __launch_bounds__(256) void init_hh_tok(
    const float* __restrict__ h_f, const float* __restrict__ h_b,
    const int* __restrict__ tgt, float* __restrict__ hh, int* __restrict__ tok)
{
    int i = blockIdx.x * blockDim.x + threadIdx.x;
    int b = i >> 11, j = i & 2047;
    hh[i] = (j < H) ? h_f[(size_t)b * H + j] : h_b[(size_t)b * H + (j - H)];
    if (j == 0) tok[b] = tgt[b * T];
}

// ===========================================================================
extern "C" void kernel_launch(void* const* d_in, const int* in_sizes, int n_in,
                              void* d_out, int out_size, void* d_ws, size_t ws_size,
                              hipStream_t stream)
{
    const int*   src     = (const int*)d_in[0];
    const int*   tgt     = (const int*)d_in[1];
    const float* enc_emb = (const float*)d_in[2];
    const float* dec_emb = (const float*)d_in[3];
    const float* W_ih_f  = (const float*)d_in[4];
    const float* W_hh_f  = (const float*)d_in[5];
    const float* b_ih_f  = (const float*)d_in[6];
    const float* b_hh_f  = (const float*)d_in[7];
    const float* W_ih_b  = (const float*)d_in[8];
    const float* W_hh_b  = (const float*)d_in[9];
    const float* b_ih_b  = (const float*)d_in[10];
    const float* b_hh_b  = (const float*)d_in[11];
    const float* W_ih_d  = (const float*)d_in[12];
    const float* W_hh_d  = (const float*)d_in[13];
    const float* b_ih_d  = (const float*)d_in[14];
    const float* b_hh_d  = (const float*)d_in[15];
    const float* W_fc    = (const float*)d_in[16];
    const float* b_fc    = (const float*)d_in[17];
    float* out = (float*)d_out;

    // ---------------- workspace layout (identical to prior session) --------
    char* base = (char*)d_ws;
    size_t off = 0;
    auto alloc = [&](size_t bytes) { char* p = base + off; off += (bytes + 255) & ~(size_t)255; return p; };

    float*   hE     = (float*)  alloc((size_t)2 * B * H * 4);      // zeroed with planes below
    ushortT* hE_hi  = (ushortT*)alloc((size_t)2 * B * H * 2);      // plane buf A
    ushortT* hE_lo  = (ushortT*)alloc((size_t)2 * B * H * 2);
    float*   hh     = (float*)  alloc((size_t)B * H2 * 4);
    ushortT* hh_hi  = (ushortT*)alloc((size_t)B * H2 * 2);         // plane buf A
    ushortT* hh_lo  = (ushortT*)alloc((size_t)B * H2 * 2);
    float*   ghE    = (float*)  alloc((size_t)2 * 2 * B * H3 * 4); // fused path: plane buf B overlay; fallback: gi/gh
    float*   giTabF = (float*)  alloc((size_t)VOUTD * H3 * 4);
    float*   giTabB = (float*)  alloc((size_t)VOUTD * H3 * 4);
    float*   giTabD = (float*)  alloc((size_t)VOUTD * H6 * 4);
    ushortT* Whhf_hi = (ushortT*)alloc((size_t)H3 * H * 2);
    ushortT* Whhf_lo = (ushortT*)alloc((size_t)H3 * H * 2);
    ushortT* Whhb_hi = (ushortT*)alloc((size_t)H3 * H * 2);
    ushortT* Whhb_lo = (ushortT*)alloc((size_t)H3 * H * 2);
    ushortT* Whhd_hi = (ushortT*)alloc((size_t)H6 * H2 * 2);
    ushortT* Whhd_lo = (ushortT*)alloc((size_t)H6 * H2 * 2);
    int*     tok    = (int*)    alloc((size_t)B * 4);
    float*   giE    = ghE;                                         // fallback gi
    size_t required = off;

    // plane buf B carved from ghE (25MB region; fused path never uses ghE)
    char* ghBase = (char*)ghE;
    ushortT* hE_hiB = (ushortT*)(ghBase);
    ushortT* hE_loB = (ushortT*)(ghBase + (size_t)2 * B * H * 2);
    ushortT* hh_hiB = (ushortT*)(ghBase + (size_t)4 * B * H * 2);
    ushortT* hh_loB = (ushortT*)(ghBase + (size_t)4 * B * H * 2 + (size_t)B * H2 * 2);

    dim3 blk(256);

    if (ws_size >= required) {
        // =================== fused split-bf16 MFMA path ===================
        {   // zero hE + hE_hi + hE_lo (contiguous)
            size_t zbytes = (size_t)2 * B * H * 4 + 2 * ((size_t)2 * B * H * 2);
            int n16 = (int)(zbytes / 16);
            zero16<<<dim3((n16 + 255) / 256), blk, 0, stream>>>((uint4*)hE, n16);
        }
        auto split = [&](const float* x, ushortT* hi, ushortT* lo, size_t n) {
            int n4 = (int)(n / 4);
            split_bf16<<<dim3((n4 + 255) / 256), blk, 0, stream>>>(
                (const float4*)x, (uint2*)hi, (uint2*)lo, n4);
        };
        split(W_hh_f, Whhf_hi, Whhf_lo, (size_t)H3 * H);
        split(W_hh_b, Whhb_hi, Whhb_lo, (size_t)H3 * H);
        split(W_hh_d, Whhd_hi, Whhd_lo, (size_t)H6 * H2);

        // gi tables (exact fp32): emb @ W_ih^T + b_ih, M=128
        gemm_bias<<<dim3(H3 / 64, VOUTD / 64), blk, 0, stream>>>(
            enc_emb, nullptr, 0, 0, E, W_ih_f, b_ih_f, giTabF, H3, E);
        gemm_bias<<<dim3(H3 / 64, VOUTD / 64), blk, 0, stream>>>(
            enc_emb, nullptr, 0, 0, E, W_ih_b, b_ih_b, giTabB, H3, E);
        gemm_bias<<<dim3(H6 / 64, VOUTD / 64), blk, 0, stream>>>(
            dec_emb, nullptr, 0, 0, E, W_ih_d, b_ih_d, giTabD, H6, E);

        // ---------------- Encoder: 64 fused steps ----------------
        for (int s = 0; s < S; ++s) {
            const ushortT* inHi = (s & 1) ? hE_hiB : hE_hi;
            const ushortT* inLo = (s & 1) ? hE_loB : hE_lo;
            ushortT* outHi = (s & 1) ? hE_hi : hE_hiB;
            ushortT* outLo = (s & 1) ? hE_lo : hE_loB;
            fused_step_enc<<<dim3(512), blk, 0, stream>>>(
                inHi, inLo, Whhf_hi, Whhf_lo, Whhb_hi, Whhb_lo,
                giTabF, giTabB, src, s, b_hh_f, b_hh_b,
                hE, outHi, outLo);
        }

        init_hh_tok_split<<<dim3((B * H2) / 256), blk, 0, stream>>>(
            hE, hE + (size_t)B * H, tgt, hh, hh_hi, hh_lo, tok);

        // ---------------- Decoder: 31 fused steps ----------------
        for (int t = 0; t < T - 1; ++t) {
            const ushortT* inHi = (t & 1) ? hh_hiB : hh_hi;
            const ushortT* inLo = (t & 1) ? hh_loB : hh_lo;
            ushortT* outHi = (t & 1) ? hh_hi : hh_hiB;
            ushortT* outLo = (t & 1) ? hh_lo : hh_loB;
            fused_step_dec<<<dim3(512), blk, 0, stream>>>(
                inHi, inLo, Whhd_hi, Whhd_lo, giTabD, tok, b_hh_d,
                hh, outHi, outLo);
            logits_argmax<<<dim3(B), dim3(128), 0, stream>>>(hh, W_fc, b_fc, out, tok, t);
        }
    } else {
        // =================== fp32 fallback (R1-proven path) ===================
        {
            size_t zbytes = (size_t)2 * B * H * 4;
            int n16 = (int)(zbytes / 16);
            zero16<<<dim3((n16 + 255) / 256), blk, 0, stream>>>((uint4*)hE, n16);
        }
        float* ghF = giE + (size_t)2 * B * H3;   // second half of ghE region
        dim3 grid_gi(H3 / 64, (2 * B) / 64);
        dim3 grid_gate((2 * B * H) / 256);
        for (int s = 0; s < S; ++s) {
            gemm_enc<<<grid_gi, blk, 0, stream>>>(enc_emb, E, E, src, s,
                                                  W_ih_f, b_ih_f, W_ih_b, b_ih_b, giE, H3);
            gemm_enc<<<grid_gi, blk, 0, stream>>>(hE, H, H, nullptr, 0,
                                                  W_hh_f, b_hh_f, W_hh_b, b_hh_b, ghF, H3);
            gru_gate<<<grid_gate, blk, 0, stream>>>(giE, ghF, hE, H);
        }
        init_hh_tok<<<dim3((B * H2) / 256), blk, 0, stream>>>(hE, hE + (size_t)B * H, tgt, hh, tok);
        dim3 grid_d(H6 / 64, B / 64);
        dim3 grid_dgate((B * H2) / 256);
        for (int t = 0; t < T - 1; ++t) {
            gemm_bias<<<grid_d, blk, 0, stream>>>(dec_emb, tok, 1, 0, E,
                                                  W_ih_d, b_ih_d, giE, H6, E);
            gemm_bias<<<grid_d, blk, 0, stream>>>(hh, nullptr, 0, 0, H2,
                                                  W_hh_d, b_hh_d, ghF, H6, H2);
            gru_gate<<<grid_dgate, blk, 0, stream>>>(giE, ghF, hh, H2);
            logits_argmax<<<dim3(B), dim3(128), 0, stream>>>(hh, W_fc, b_fc, out, tok, t);
        }
    }
}

// Round 2
// 5248.010 us; speedup vs baseline: 2.1131x; 1.1252x over previous
//
#include <hip/hip_runtime.h>
#include <math.h>

#define B 512
#define S 64
#define T 32
#define E 512
#define H 1024
#define VOUTD 128
#define H2 (2*H)
#define H3 (3*H)
#define H6 (6*H)

// padded LDS row stride (shorts): 40 shorts = 80 B, 16B-aligned, rows spread
// over 16 distinct bank starts (only free 2-way aliasing on b128 reads).
#define LDR 40

typedef unsigned short ushortT;
typedef unsigned int uintT;
typedef __attribute__((ext_vector_type(8))) short short8;
typedef __attribute__((ext_vector_type(4))) float floatx4;

__device__ __forceinline__ float sigmoidf_(float x) { return 1.0f / (1.0f + expf(-x)); }

// ===========================================================================
// Split fp32 -> bf16 hi/lo planes. hi = trunc16(x), lo = trunc16(x - hi).
// ===========================================================================
__global__ __launch_bounds__(256) void split_bf16(
    const float4* __restrict__ x, uint2* __restrict__ hi, uint2* __restrict__ lo, int n4)
{
    int i = blockIdx.x * 256 + threadIdx.x;
    if (i >= n4) return;
    float4 v = x[i];
    uintT ux = __float_as_uint(v.x), uy = __float_as_uint(v.y);
    uintT uz = __float_as_uint(v.z), uw = __float_as_uint(v.w);
    uintT lx = __float_as_uint(v.x - __uint_as_float(ux & 0xFFFF0000u)) >> 16;
    uintT ly = __float_as_uint(v.y - __uint_as_float(uy & 0xFFFF0000u)) >> 16;
    uintT lz = __float_as_uint(v.z - __uint_as_float(uz & 0xFFFF0000u)) >> 16;
    uintT lw = __float_as_uint(v.w - __uint_as_float(uw & 0xFFFF0000u)) >> 16;
    hi[i] = make_uint2((ux >> 16) | (uy & 0xFFFF0000u), (uz >> 16) | (uw & 0xFFFF0000u));
    lo[i] = make_uint2(lx | (ly << 16), lz | (lw << 16));
}

__global__ __launch_bounds__(256) void zero16(uint4* __restrict__ p, int n)
{
    int i = blockIdx.x * 256 + threadIdx.x;
    if (i < n) p[i] = make_uint4(0u, 0u, 0u, 0u);
}

// ===========================================================================
// FUSED recurrent step (encoder). Single barrier per K-chunk: loads for the
// next chunk are issued before the MFMA phase, and the LDS writes go to the
// spare buffer (p^1) BEFORE the barrier (race-free: readers are on p).
// LDS rows padded to LDR=40 shorts to kill the 8-way b128 read conflict.
// ===========================================================================
__global__ __launch_bounds__(256) void fused_step_enc(
    const ushortT* __restrict__ Ahi, const ushortT* __restrict__ Alo,   // in planes [2B][H]
    const ushortT* __restrict__ Whi_f, const ushortT* __restrict__ Wlo_f,
    const ushortT* __restrict__ Whi_b, const ushortT* __restrict__ Wlo_b,
    const float* __restrict__ giTabF, const float* __restrict__ giTabB,
    const int* __restrict__ src, int s,
    const float* __restrict__ bhF, const float* __restrict__ bhB,
    float* __restrict__ h,                                              // fp32 [2B][H]
    ushortT* __restrict__ hiOut, ushortT* __restrict__ loOut)           // out planes
{
    __shared__ ushortT sAh[2][64 * LDR], sAl[2][64 * LDR];
    __shared__ ushortT sBh[2][96 * LDR], sBl[2][96 * LDR];
    __shared__ int sTok[64];

    const int t    = threadIdx.x;
    const int lane = t & 63;
    const int w    = t >> 6;

    const int bid = blockIdx.x;
    const int xcd = bid & 7;
    const int q   = bid >> 3;
    const int jg  = xcd + 8 * (q & 3);
    const int mb  = q >> 2;
    const int j0  = jg * 32;
    const int m0  = mb * 64;
    const bool bwd = (m0 >= B);

    const ushortT* Whi   = bwd ? Whi_b : Whi_f;
    const ushortT* Wlo   = bwd ? Wlo_b : Wlo_f;
    const float*   giTab = bwd ? giTabB : giTabF;
    const float*   bh    = bwd ? bhB : bhF;

    if (t < 64) {
        int b = (m0 + t) & (B - 1);
        sTok[t] = src[b * S + (bwd ? (S - 1 - s) : s)];
    }

    const int kseg = (t & 3) * 8;
    const ushortT* gAh = Ahi + (size_t)(m0 + (t >> 2)) * H + kseg;
    const ushortT* gAl = Alo + (size_t)(m0 + (t >> 2)) * H + kseg;
    const int brow0 = t >> 2;
    const int wr0   = (brow0 >> 5) * H + j0 + (brow0 & 31);
    const ushortT* gBh0 = Whi + (size_t)wr0 * H + kseg;
    const ushortT* gBl0 = Wlo + (size_t)wr0 * H + kseg;
    const int brow1 = 64 + (t >> 2);
    const int wr1   = (brow1 >> 5) * H + j0 + (brow1 & 31);
    const ushortT* gBh1 = Whi + (size_t)wr1 * H + kseg;
    const ushortT* gBl1 = Wlo + (size_t)wr1 * H + kseg;
    const int ldsA  = (t >> 2) * LDR + kseg;
    const int ldsB0 = (t >> 2) * LDR + kseg;
    const int ldsB1 = (64 + (t >> 2)) * LDR + kseg;
    const bool doB1 = (t < 128);   // waves 0,1 only -> wave-uniform

    const int koff = (lane >> 4) * 8;
    const int rA0  = (w >> 1) * 32 + (lane & 15);
    const int rB0  = (w & 1) * 16 + (lane & 15);

    floatx4 acc[2][3];
#pragma unroll
    for (int mi = 0; mi < 2; ++mi)
#pragma unroll
        for (int g = 0; g < 3; ++g) acc[mi][g] = (floatx4){0.f, 0.f, 0.f, 0.f};

    uint4 vAh, vAl, vBh0, vBl0, vBh1 = {}, vBl1 = {};
    vAh  = *(const uint4*)gAh;  vAl  = *(const uint4*)gAl;
    vBh0 = *(const uint4*)gBh0; vBl0 = *(const uint4*)gBl0;
    if (doB1) { vBh1 = *(const uint4*)gBh1; vBl1 = *(const uint4*)gBl1; }
    *(uint4*)&sAh[0][ldsA]  = vAh;  *(uint4*)&sAl[0][ldsA]  = vAl;
    *(uint4*)&sBh[0][ldsB0] = vBh0; *(uint4*)&sBl[0][ldsB0] = vBl0;
    if (doB1) { *(uint4*)&sBh[0][ldsB1] = vBh1; *(uint4*)&sBl[0][ldsB1] = vBl1; }
    __syncthreads();

    int p = 0;
    const int nCh = H / 32;
    for (int ck = 0; ck < nCh; ++ck) {
        const bool hasNext = (ck + 1 < nCh);
        if (hasNext) {
            const int k0 = (ck + 1) * 32;
            vAh  = *(const uint4*)(gAh + k0);  vAl  = *(const uint4*)(gAl + k0);
            vBh0 = *(const uint4*)(gBh0 + k0); vBl0 = *(const uint4*)(gBl0 + k0);
            if (doB1) { vBh1 = *(const uint4*)(gBh1 + k0); vBl1 = *(const uint4*)(gBl1 + k0); }
        }
        short8 fah[2], fal[2], fbh[3], fbl[3];
#pragma unroll
        for (int mi = 0; mi < 2; ++mi) {
            fah[mi] = *(const short8*)&sAh[p][(rA0 + mi * 16) * LDR + koff];
            fal[mi] = *(const short8*)&sAl[p][(rA0 + mi * 16) * LDR + koff];
        }
#pragma unroll
        for (int g = 0; g < 3; ++g) {
            fbh[g] = *(const short8*)&sBh[p][(rB0 + g * 32) * LDR + koff];
            fbl[g] = *(const short8*)&sBl[p][(rB0 + g * 32) * LDR + koff];
        }
#pragma unroll
        for (int mi = 0; mi < 2; ++mi)
#pragma unroll
            for (int g = 0; g < 3; ++g) {
                acc[mi][g] = __builtin_amdgcn_mfma_f32_16x16x32_bf16(fah[mi], fbh[g], acc[mi][g], 0, 0, 0);
                acc[mi][g] = __builtin_amdgcn_mfma_f32_16x16x32_bf16(fah[mi], fbl[g], acc[mi][g], 0, 0, 0);
                acc[mi][g] = __builtin_amdgcn_mfma_f32_16x16x32_bf16(fal[mi], fbh[g], acc[mi][g], 0, 0, 0);
            }
        if (hasNext) {
            const int pq = p ^ 1;
            // write to the spare buffer BEFORE the single barrier (readers on p)
            *(uint4*)&sAh[pq][ldsA]  = vAh;  *(uint4*)&sAl[pq][ldsA]  = vAl;
            *(uint4*)&sBh[pq][ldsB0] = vBh0; *(uint4*)&sBl[pq][ldsB0] = vBl0;
            if (doB1) { *(uint4*)&sBh[pq][ldsB1] = vBh1; *(uint4*)&sBl[pq][ldsB1] = vBl1; }
            __syncthreads();
            p = pq;
        }
    }

    // fused gate epilogue: r/z/n for (row,colj) are in-lane.
    const int colj = j0 + (w & 1) * 16 + (lane & 15);
    const float bR = bh[colj], bZ = bh[H + colj], bN = bh[2 * H + colj];
    const int rloc0 = (w >> 1) * 32 + (lane >> 4) * 4;
#pragma unroll
    for (int mi = 0; mi < 2; ++mi) {
#pragma unroll
        for (int r = 0; r < 4; ++r) {
            const int rloc = rloc0 + mi * 16 + r;
            const int row  = m0 + rloc;
            const float* gi = giTab + (size_t)sTok[rloc] * H3;
            float ghr = acc[mi][0][r] + bR;
            float ghz = acc[mi][1][r] + bZ;
            float ghn = acc[mi][2][r] + bN;
            float rr = sigmoidf_(gi[colj] + ghr);
            float z  = sigmoidf_(gi[H + colj] + ghz);
            float n  = tanhf(gi[2 * H + colj] + rr * ghn);
            const size_t idx = (size_t)row * H + colj;
            float hnew = (1.0f - z) * n + z * h[idx];
            h[idx] = hnew;
            uintT u = __float_as_uint(hnew);
            hiOut[idx] = (ushortT)(u >> 16);
            loOut[idx] = (ushortT)(__float_as_uint(hnew - __uint_as_float(u & 0xFFFF0000u)) >> 16);
        }
    }
}

// ===========================================================================
// FUSED recurrent step (decoder): Hd = 2H, gates at {j, 2H+j, 4H+j}.
// Same single-barrier + padded-LDS structure.
// ===========================================================================
__global__ __launch_bounds__(256) void fused_step_dec(
    const ushortT* __restrict__ Ahi, const ushortT* __restrict__ Alo,   // in planes [B][2H]
    const ushortT* __restrict__ Whi, const ushortT* __restrict__ Wlo,   // [6H][2H]
    const float* __restrict__ giTabD, const int* __restrict__ tok,
    const float* __restrict__ bhD,
    float* __restrict__ h,                                              // fp32 [B][2H]
    ushortT* __restrict__ hiOut, ushortT* __restrict__ loOut)
{
    __shared__ ushortT sAh[2][64 * LDR], sAl[2][64 * LDR];
    __shared__ ushortT sBh[2][96 * LDR], sBl[2][96 * LDR];
    __shared__ int sTok[64];

    const int t    = threadIdx.x;
    const int lane = t & 63;
    const int w    = t >> 6;

    const int bid = blockIdx.x;
    const int xcd = bid & 7;
    const int q   = bid >> 3;
    const int jg  = xcd + 8 * (q & 7);   // [0,64)
    const int mb  = q >> 3;              // [0,8)
    const int j0  = jg * 32;
    const int m0  = mb * 64;

    if (t < 64) sTok[t] = tok[m0 + t];

    const int kseg = (t & 3) * 8;
    const ushortT* gAh = Ahi + (size_t)(m0 + (t >> 2)) * H2 + kseg;
    const ushortT* gAl = Alo + (size_t)(m0 + (t >> 2)) * H2 + kseg;
    const int brow0 = t >> 2;
    const int wr0   = (brow0 >> 5) * H2 + j0 + (brow0 & 31);
    const ushortT* gBh0 = Whi + (size_t)wr0 * H2 + kseg;
    const ushortT* gBl0 = Wlo + (size_t)wr0 * H2 + kseg;
    const int brow1 = 64 + (t >> 2);
    const int wr1   = (brow1 >> 5) * H2 + j0 + (brow1 & 31);
    const ushortT* gBh1 = Whi + (size_t)wr1 * H2 + kseg;
    const ushortT* gBl1 = Wlo + (size_t)wr1 * H2 + kseg;
    const int ldsA  = (t >> 2) * LDR + kseg;
    const int ldsB0 = (t >> 2) * LDR + kseg;
    const int ldsB1 = (64 + (t >> 2)) * LDR + kseg;
    const bool doB1 = (t < 128);

    const int koff = (lane >> 4) * 8;
    const int rA0  = (w >> 1) * 32 + (lane & 15);
    const int rB0  = (w & 1) * 16 + (lane & 15);

    floatx4 acc[2][3];
#pragma unroll
    for (int mi = 0; mi < 2; ++mi)
#pragma unroll
        for (int g = 0; g < 3; ++g) acc[mi][g] = (floatx4){0.f, 0.f, 0.f, 0.f};

    uint4 vAh, vAl, vBh0, vBl0, vBh1 = {}, vBl1 = {};
    vAh  = *(const uint4*)gAh;  vAl  = *(const uint4*)gAl;
    vBh0 = *(const uint4*)gBh0; vBl0 = *(const uint4*)gBl0;
    if (doB1) { vBh1 = *(const uint4*)gBh1; vBl1 = *(const uint4*)gBl1; }
    *(uint4*)&sAh[0][ldsA]  = vAh;  *(uint4*)&sAl[0][ldsA]  = vAl;
    *(uint4*)&sBh[0][ldsB0] = vBh0; *(uint4*)&sBl[0][ldsB0] = vBl0;
    if (doB1) { *(uint4*)&sBh[0][ldsB1] = vBh1; *(uint4*)&sBl[0][ldsB1] = vBl1; }
    __syncthreads();

    int p = 0;
    const int nCh = H2 / 32;
    for (int ck = 0; ck < nCh; ++ck) {
        const bool hasNext = (ck + 1 < nCh);
        if (hasNext) {
            const int k0 = (ck + 1) * 32;
            vAh  = *(const uint4*)(gAh + k0);  vAl  = *(const uint4*)(gAl + k0);
            vBh0 = *(const uint4*)(gBh0 + k0); vBl0 = *(const uint4*)(gBl0 + k0);
            if (doB1) { vBh1 = *(const uint4*)(gBh1 + k0); vBl1 = *(const uint4*)(gBl1 + k0); }
        }
        short8 fah[2], fal[2], fbh[3], fbl[3];
#pragma unroll
        for (int mi = 0; mi < 2; ++mi) {
            fah[mi] = *(const short8*)&sAh[p][(rA0 + mi * 16) * LDR + koff];
            fal[mi] = *(const short8*)&sAl[p][(rA0 + mi * 16) * LDR + koff];
        }
#pragma unroll
        for (int g = 0; g < 3; ++g) {
            fbh[g] = *(const short8*)&sBh[p][(rB0 + g * 32) * LDR + koff];
            fbl[g] = *(const short8*)&sBl[p][(rB0 + g * 32) * LDR + koff];
        }
#pragma unroll
        for (int mi = 0; mi < 2; ++mi)
#pragma unroll
            for (int g = 0; g < 3; ++g) {
                acc[mi][g] = __builtin_amdgcn_mfma_f32_16x16x32_bf16(fah[mi], fbh[g], acc[mi][g], 0, 0, 0);
                acc[mi][g] = __builtin_amdgcn_mfma_f32_16x16x32_bf16(fah[mi], fbl[g], acc[mi][g], 0, 0, 0);
                acc[mi][g] = __builtin_amdgcn_mfma_f32_16x16x32_bf16(fal[mi], fbh[g], acc[mi][g], 0, 0, 0);
            }
        if (hasNext) {
            const int pq = p ^ 1;
            *(uint4*)&sAh[pq][ldsA]  = vAh;  *(uint4*)&sAl[pq][ldsA]  = vAl;
            *(uint4*)&sBh[pq][ldsB0] = vBh0; *(uint4*)&sBl[pq][ldsB0] = vBl0;
            if (doB1) { *(uint4*)&sBh[pq][ldsB1] = vBh1; *(uint4*)&sBl[pq][ldsB1] = vBl1; }
            __syncthreads();
            p = pq;
        }
    }

    const int colj = j0 + (w & 1) * 16 + (lane & 15);
    const float bR = bhD[colj], bZ = bhD[H2 + colj], bN = bhD[2 * H2 + colj];
    const int rloc0 = (w >> 1) * 32 + (lane >> 4) * 4;
#pragma unroll
    for (int mi = 0; mi < 2; ++mi) {
#pragma unroll
        for (int r = 0; r < 4; ++r) {
            const int rloc = rloc0 + mi * 16 + r;
            const int row  = m0 + rloc;
            const float* gi = giTabD + (size_t)sTok[rloc] * H6;
            float ghr = acc[mi][0][r] + bR;
            float ghz = acc[mi][1][r] + bZ;
            float ghn = acc[mi][2][r] + bN;
            float rr = sigmoidf_(gi[colj] + ghr);
            float z  = sigmoidf_(gi[H2 + colj] + ghz);
            float n  = tanhf(gi[2 * H2 + colj] + rr * ghn);
            const size_t idx = (size_t)row * H2 + colj;
            float hnew = (1.0f - z) * n + z * h[idx];
            h[idx] = hnew;
            uintT u = __float_as_uint(hnew);
            hiOut[idx] = (ushortT)(u >> 16);
            loOut[idx] = (ushortT)(__float_as_uint(hnew - __uint_as_float(u & 0xFFFF0000u)) >> 16);
        }
    }
}

// hh[b,0:H]=h_f[b], hh[b,H:2H]=h_b[b] (+ bf16 planes); tok[b]=tgt[b,0]
__global__ __launch_bounds__(256) void init_hh_tok_split(
    const float* __restrict__ h_f, const float* __restrict__ h_b,
    const int* __restrict__ tgt, float* __restrict__ hh,
    ushortT* __restrict__ hh_hi, ushortT* __restrict__ hh_lo, int* __restrict__ tok)
{
    int i = blockIdx.x * blockDim.x + threadIdx.x;   // over B*2H
    int b = i >> 11;
    int j = i & 2047;
    float v = (j < H) ? h_f[(size_t)b * H + j] : h_b[(size_t)b * H + (j - H)];
    hh[i] = v;
    uintT u = __float_as_uint(v);
    hh_hi[i] = (ushortT)(u >> 16);
    hh_lo[i] = (ushortT)(__float_as_uint(v - __uint_as_float(u & 0xFFFF0000u)) >> 16);
    if (j == 0) tok[b] = tgt[b * T];
}

// ===========================================================================
// logits = hh @ W_fc^T + b_fc (V=128) + argmax. Parallel version: 2 batch
// rows per block, 256 threads = 128 cols x 2 k-halves; hh rows staged in LDS
// (broadcast reads); exact fp32 math; first-index tie argmax.
// Grid = B/2 = 256 blocks (full CU coverage vs old 2-wave-512-block version).
// ===========================================================================
__global__ __launch_bounds__(256) void logits_argmax2(
    const float* __restrict__ hh, const float* __restrict__ W_fc,
    const float* __restrict__ b_fc, float* __restrict__ out,
    int* __restrict__ tok, int t)
{
    __shared__ float sh[2][H2];          // 16 KB
    __shared__ float sred[2][2][128];    // [khalf][row][col]
    __shared__ float sval[2][128];
    __shared__ int   sidx[2][128];
    const int tid = threadIdx.x;
    const int col = tid & 127;
    const int kh  = tid >> 7;            // 0/1
    const int b0  = blockIdx.x * 2;

    {   // stage 2 hh rows (coalesced float4)
        const float4* srcp = (const float4*)(hh + (size_t)b0 * H2);
        float4* dst = (float4*)sh;
        for (int i = tid; i < 2 * H2 / 4; i += 256) dst[i] = srcp[i];
    }
    __syncthreads();

    const float* wrow = W_fc + (size_t)col * H2 + kh * (H2 / 2);
    const float* s0 = sh[0] + kh * (H2 / 2);
    const float* s1 = sh[1] + kh * (H2 / 2);
    float a0 = 0.f, a1 = 0.f;
#pragma unroll 8
    for (int k = 0; k < H2 / 2; k += 4) {
        float4 w4 = *(const float4*)(wrow + k);
        float4 h0 = *(const float4*)(s0 + k);
        float4 h1 = *(const float4*)(s1 + k);
        a0 += w4.x * h0.x + w4.y * h0.y + w4.z * h0.z + w4.w * h0.w;
        a1 += w4.x * h1.x + w4.y * h1.y + w4.z * h1.z + w4.w * h1.w;
    }
    sred[kh][0][col] = a0;
    sred[kh][1][col] = a1;
    __syncthreads();

    if (kh == 0) {
        float l0 = sred[0][0][col] + sred[1][0][col] + b_fc[col];
        float l1 = sred[0][1][col] + sred[1][1][col] + b_fc[col];
        out[(size_t)(b0 + 0) * ((T - 1) * VOUTD) + (size_t)t * VOUTD + col] = l0;
        out[(size_t)(b0 + 1) * ((T - 1) * VOUTD) + (size_t)t * VOUTD + col] = l1;
        sval[0][col] = l0; sidx[0][col] = col;
        sval[1][col] = l1; sidx[1][col] = col;
    }
    __syncthreads();

    // argmax: 2 rows reduced in parallel (r = tid>>7, c = tid&127)
    const int r = tid >> 7, c = tid & 127;
    for (int off = 64; off > 0; off >>= 1) {
        if (c < off) {
            float ov = sval[r][c + off]; int oi = sidx[r][c + off];
            if (ov > sval[r][c] || (ov == sval[r][c] && oi < sidx[r][c])) {
                sval[r][c] = ov; sidx[r][c] = oi;
            }
        }
        __syncthreads();
    }
    if (tid < 2) tok[b0 + tid] = sidx[tid][0];
}

// ===========================================================================
// fp32 vector GEMM (R1-proven): C[M,N] = A @ W^T + bias. Used for the tiny
// gi-table precomputes (exact fp32) and as full fallback path.
// ===========================================================================
__global__ __launch_bounds__(256) void gemm_bias(
    const float* __restrict__ Abase,
    const int* __restrict__ idx, int idxStride, int idxOff, int lda,
    const float* __restrict__ W, const float* __restrict__ bias,
    float* __restrict__ C, int N, int K)
{
    __shared__ float As[16][68];
    __shared__ float Ws[16][68];
    const int t = threadIdx.x;
    const int m0 = blockIdx.y * 64, n0 = blockIdx.x * 64;
    const int lr = t >> 2, lc = (t & 3) << 2;
    const int tx = t & 15, ty = t >> 4;
    const int tn0 = tx << 2, tm0 = ty << 2;
    const int arow = m0 + lr;
    const float* Aptr = idx ? (Abase + (size_t)idx[arow * idxStride + idxOff] * lda)
                            : (Abase + (size_t)arow * lda);
    const float* Wptr = W + (size_t)(n0 + lr) * K;
    float acc[4][4] = {{0.f}};
    for (int k0 = 0; k0 < K; k0 += 16) {
        float4 a4 = *(const float4*)(Aptr + k0 + lc);
        float4 w4 = *(const float4*)(Wptr + k0 + lc);
        __syncthreads();
        As[lc+0][lr] = a4.x; As[lc+1][lr] = a4.y; As[lc+2][lr] = a4.z; As[lc+3][lr] = a4.w;
        Ws[lc+0][lr] = w4.x; Ws[lc+1][lr] = w4.y; Ws[lc+2][lr] = w4.z; Ws[lc+3][lr] = w4.w;
        __syncthreads();
#pragma unroll
        for (int kk = 0; kk < 16; ++kk) {
            float4 av = *(const float4*)&As[kk][tm0];
            float4 wv = *(const float4*)&Ws[kk][tn0];
            float am[4] = {av.x, av.y, av.z, av.w};
            float wn[4] = {wv.x, wv.y, wv.z, wv.w};
#pragma unroll
            for (int i = 0; i < 4; ++i)
#pragma unroll
                for (int j = 0; j < 4; ++j) acc[i][j] += am[i] * wn[j];
        }
    }
    const float b0 = bias[n0+tn0], b1 = bias[n0+tn0+1], b2 = bias[n0+tn0+2], b3 = bias[n0+tn0+3];
#pragma unroll
    for (int i = 0; i < 4; ++i) {
        float4 o = make_float4(acc[i][0]+b0, acc[i][1]+b1, acc[i][2]+b2, acc[i][3]+b3);
        *(float4*)(C + (size_t)(m0 + tm0 + i) * N + n0 + tn0) = o;
    }
}

__global__ __launch_bounds__(256) void gemm_enc(
    const float* __restrict__ Abase, int lda, int K,
    const int* __restrict__ srcIdx, int s,
    const float* __restrict__ W1, const float* __restrict__ bias1,
    const float* __restrict__ W2, const float* __restrict__ bias2,
    float* __restrict__ C, int N)
{
    __shared__ float As[16][68];
    __shared__ float Ws[16][68];
    const int t = threadIdx.x;
    const int m0 = blockIdx.y * 64, n0 = blockIdx.x * 64;
    const bool bwd = (m0 >= B);
    const float* W = bwd ? W2 : W1;
    const float* bias = bwd ? bias2 : bias1;
    const int lr = t >> 2, lc = (t & 3) << 2;
    const int tx = t & 15, ty = t >> 4;
    const int tn0 = tx << 2, tm0 = ty << 2;
    const int arow = m0 + lr;
    const float* Aptr;
    if (srcIdx) {
        int r = arow & (B - 1);
        int sidx = bwd ? (S - 1 - s) : s;
        Aptr = Abase + (size_t)srcIdx[r * S + sidx] * lda;
    } else Aptr = Abase + (size_t)arow * lda;
    const float* Wptr = W + (size_t)(n0 + lr) * K;
    float acc[4][4] = {{0.f}};
    for (int k0 = 0; k0 < K; k0 += 16) {
        float4 a4 = *(const float4*)(Aptr + k0 + lc);
        float4 w4 = *(const float4*)(Wptr + k0 + lc);
        __syncthreads();
        As[lc+0][lr] = a4.x; As[lc+1][lr] = a4.y; As[lc+2][lr] = a4.z; As[lc+3][lr] = a4.w;
        Ws[lc+0][lr] = w4.x; Ws[lc+1][lr] = w4.y; Ws[lc+2][lr] = w4.z; Ws[lc+3][lr] = w4.w;
        __syncthreads();
#pragma unroll
        for (int kk = 0; kk < 16; ++kk) {
            float4 av = *(const float4*)&As[kk][tm0];
            float4 wv = *(const float4*)&Ws[kk][tn0];
            float am[4] = {av.x, av.y, av.z, av.w};
            float wn[4] = {wv.x, wv.y, wv.z, wv.w};
#pragma unroll
            for (int i = 0; i < 4; ++i)
#pragma unroll
                for (int j = 0; j < 4; ++j) acc[i][j] += am[i] * wn[j];
        }
    }
    const float b0 = bias[n0+tn0], b1 = bias[n0+tn0+1], b2 = bias[n0+tn0+2], b3 = bias[n0+tn0+3];
#pragma unroll
    for (int i = 0; i < 4; ++i) {
        float4 o = make_float4(acc[i][0]+b0, acc[i][1]+b1, acc[i][2]+b2, acc[i][3]+b3);
        *(float4*)(C + (size_t)(m0 + tm0 + i) * N + n0 + tn0) = o;
    }
}

__global__ __launch_bounds__(256) void gru_gate(
    const float* __restrict__ gi, const float* __restrict__ gh,
    float* __restrict__ h, int Hd)
{
    int i = blockIdx.x * blockDim.x + threadIdx.x;
    int b = i / Hd, j = i - b * Hd;
    const float* gib = gi + (size_t)b * 3 * Hd;
    const float* ghb = gh + (size_t)b * 3 * Hd;
    float r = sigmoidf_(gib[j] + ghb[j]);
    float z = sigmoidf_(gib[Hd + j] + ghb[Hd + j]);
    float n = tanhf(gib[2 * Hd + j] + r * ghb[2 * Hd + j]);
    h[i] = (1.0f - z) * n + z * h[i];
}

__global__ __launch_bounds__(256) void init_hh_tok(
    const float* __restrict__ h_f, const float* __restrict__ h_b,
    const int* __restrict__ tgt, float* __restrict__ hh, int* __restrict__ tok)
{
    int i = blockIdx.x * blockDim.x + threadIdx.x;
    int b = i >> 11, j = i & 2047;
    hh[i] = (j < H) ? h_f[(size_t)b * H + j] : h_b[(size_t)b * H + (j - H)];
    if (j == 0) tok[b] = tgt[b * T];
}

// ===========================================================================
extern "C" void kernel_launch(void* const* d_in, const int* in_sizes, int n_in,
                              void* d_out, int out_size, void* d_ws, size_t ws_size,
                              hipStream_t stream)
{
    const int*   src     = (const int*)d_in[0];
    const int*   tgt     = (const int*)d_in[1];
    const float* enc_emb = (const float*)d_in[2];
    const float* dec_emb = (const float*)d_in[3];
    const float* W_ih_f  = (const float*)d_in[4];
    const float* W_hh_f  = (const float*)d_in[5];
    const float* b_ih_f  = (const float*)d_in[6];
    const float* b_hh_f  = (const float*)d_in[7];
    const float* W_ih_b  = (const float*)d_in[8];
    const float* W_hh_b  = (const float*)d_in[9];
    const float* b_ih_b  = (const float*)d_in[10];
    const float* b_hh_b  = (const float*)d_in[11];
    const float* W_ih_d  = (const float*)d_in[12];
    const float* W_hh_d  = (const float*)d_in[13];
    const float* b_ih_d  = (const float*)d_in[14];
    const float* b_hh_d  = (const float*)d_in[15];
    const float* W_fc    = (const float*)d_in[16];
    const float* b_fc    = (const float*)d_in[17];
    float* out = (float*)d_out;

    // ---------------- workspace layout (identical to prior session) --------
    char* base = (char*)d_ws;
    size_t off = 0;
    auto alloc = [&](size_t bytes) { char* p = base + off; off += (bytes + 255) & ~(size_t)255; return p; };

    float*   hE     = (float*)  alloc((size_t)2 * B * H * 4);      // zeroed with planes below
    ushortT* hE_hi  = (ushortT*)alloc((size_t)2 * B * H * 2);      // plane buf A
    ushortT* hE_lo  = (ushortT*)alloc((size_t)2 * B * H * 2);
    float*   hh     = (float*)  alloc((size_t)B * H2 * 4);
    ushortT* hh_hi  = (ushortT*)alloc((size_t)B * H2 * 2);         // plane buf A
    ushortT* hh_lo  = (ushortT*)alloc((size_t)B * H2 * 2);
    float*   ghE    = (float*)  alloc((size_t)2 * 2 * B * H3 * 4); // fused path: plane buf B overlay; fallback: gi/gh
    float*   giTabF = (float*)  alloc((size_t)VOUTD * H3 * 4);
    float*   giTabB = (float*)  alloc((size_t)VOUTD * H3 * 4);
    float*   giTabD = (float*)  alloc((size_t)VOUTD * H6 * 4);
    ushortT* Whhf_hi = (ushortT*)alloc((size_t)H3 * H * 2);
    ushortT* Whhf_lo = (ushortT*)alloc((size_t)H3 * H * 2);
    ushortT* Whhb_hi = (ushortT*)alloc((size_t)H3 * H * 2);
    ushortT* Whhb_lo = (ushortT*)alloc((size_t)H3 * H * 2);
    ushortT* Whhd_hi = (ushortT*)alloc((size_t)H6 * H2 * 2);
    ushortT* Whhd_lo = (ushortT*)alloc((size_t)H6 * H2 * 2);
    int*     tok    = (int*)    alloc((size_t)B * 4);
    float*   giE    = ghE;                                         // fallback gi
    size_t required = off;

    // plane buf B carved from ghE (25MB region; fused path never uses ghE)
    char* ghBase = (char*)ghE;
    ushortT* hE_hiB = (ushortT*)(ghBase);
    ushortT* hE_loB = (ushortT*)(ghBase + (size_t)2 * B * H * 2);
    ushortT* hh_hiB = (ushortT*)(ghBase + (size_t)4 * B * H * 2);
    ushortT* hh_loB = (ushortT*)(ghBase + (size_t)4 * B * H * 2 + (size_t)B * H2 * 2);

    dim3 blk(256);

    if (ws_size >= required) {
        // =================== fused split-bf16 MFMA path ===================
        {   // zero hE + hE_hi + hE_lo (contiguous)
            size_t zbytes = (size_t)2 * B * H * 4 + 2 * ((size_t)2 * B * H * 2);
            int n16 = (int)(zbytes / 16);
            zero16<<<dim3((n16 + 255) / 256), blk, 0, stream>>>((uint4*)hE, n16);
        }
        auto split = [&](const float* x, ushortT* hi, ushortT* lo, size_t n) {
            int n4 = (int)(n / 4);
            split_bf16<<<dim3((n4 + 255) / 256), blk, 0, stream>>>(
                (const float4*)x, (uint2*)hi, (uint2*)lo, n4);
        };
        split(W_hh_f, Whhf_hi, Whhf_lo, (size_t)H3 * H);
        split(W_hh_b, Whhb_hi, Whhb_lo, (size_t)H3 * H);
        split(W_hh_d, Whhd_hi, Whhd_lo, (size_t)H6 * H2);

        // gi tables (exact fp32): emb @ W_ih^T + b_ih, M=128
        gemm_bias<<<dim3(H3 / 64, VOUTD / 64), blk, 0, stream>>>(
            enc_emb, nullptr, 0, 0, E, W_ih_f, b_ih_f, giTabF, H3, E);
        gemm_bias<<<dim3(H3 / 64, VOUTD / 64), blk, 0, stream>>>(
            enc_emb, nullptr, 0, 0, E, W_ih_b, b_ih_b, giTabB, H3, E);
        gemm_bias<<<dim3(H6 / 64, VOUTD / 64), blk, 0, stream>>>(
            dec_emb, nullptr, 0, 0, E, W_ih_d, b_ih_d, giTabD, H6, E);

        // ---------------- Encoder: 64 fused steps ----------------
        for (int s = 0; s < S; ++s) {
            const ushortT* inHi = (s & 1) ? hE_hiB : hE_hi;
            const ushortT* inLo = (s & 1) ? hE_loB : hE_lo;
            ushortT* outHi = (s & 1) ? hE_hi : hE_hiB;
            ushortT* outLo = (s & 1) ? hE_lo : hE_loB;
            fused_step_enc<<<dim3(512), blk, 0, stream>>>(
                inHi, inLo, Whhf_hi, Whhf_lo, Whhb_hi, Whhb_lo,
                giTabF, giTabB, src, s, b_hh_f, b_hh_b,
                hE, outHi, outLo);
        }

        init_hh_tok_split<<<dim3((B * H2) / 256), blk, 0, stream>>>(
            hE, hE + (size_t)B * H, tgt, hh, hh_hi, hh_lo, tok);

        // ---------------- Decoder: 31 fused steps ----------------
        for (int t = 0; t < T - 1; ++t) {
            const ushortT* inHi = (t & 1) ? hh_hiB : hh_hi;
            const ushortT* inLo = (t & 1) ? hh_loB : hh_lo;
            ushortT* outHi = (t & 1) ? hh_hi : hh_hiB;
            ushortT* outLo = (t & 1) ? hh_lo : hh_loB;
            fused_step_dec<<<dim3(512), blk, 0, stream>>>(
                inHi, inLo, Whhd_hi, Whhd_lo, giTabD, tok, b_hh_d,
                hh, outHi, outLo);
            logits_argmax2<<<dim3(B / 2), blk, 0, stream>>>(hh, W_fc, b_fc, out, tok, t);
        }
    } else {
        // =================== fp32 fallback (R1-proven path) ===================
        {
            size_t zbytes = (size_t)2 * B * H * 4;
            int n16 = (int)(zbytes / 16);
            zero16<<<dim3((n16 + 255) / 256), blk, 0, stream>>>((uint4*)hE, n16);
        }
        float* ghF = giE + (size_t)2 * B * H3;   // second half of ghE region
        dim3 grid_gi(H3 / 64, (2 * B) / 64);
        dim3 grid_gate((2 * B * H) / 256);
        for (int s = 0; s < S; ++s) {
            gemm_enc<<<grid_gi, blk, 0, stream>>>(enc_emb, E, E, src, s,
                                                  W_ih_f, b_ih_f, W_ih_b, b_ih_b, giE, H3);
            gemm_enc<<<grid_gi, blk, 0, stream>>>(hE, H, H, nullptr, 0,
                                                  W_hh_f, b_hh_f, W_hh_b, b_hh_b, ghF, H3);
            gru_gate<<<grid_gate, blk, 0, stream>>>(giE, ghF, hE, H);
        }
        init_hh_tok<<<dim3((B * H2) / 256), blk, 0, stream>>>(hE, hE + (size_t)B * H, tgt, hh, tok);
        dim3 grid_d(H6 / 64, B / 64);
        dim3 grid_dgate((B * H2) / 256);
        for (int t = 0; t < T - 1; ++t) {
            gemm_bias<<<grid_d, blk, 0, stream>>>(dec_emb, tok, 1, 0, E,
                                                  W_ih_d, b_ih_d, giE, H6, E);
            gemm_bias<<<grid_d, blk, 0, stream>>>(hh, nullptr, 0, 0, H2,
                                                  W_hh_d, b_hh_d, ghF, H6, H2);
            gru_gate<<<grid_dgate, blk, 0, stream>>>(giE, ghF, hh, H2);
            logits_argmax2<<<dim3(B / 2), blk, 0, stream>>>(hh, W_fc, b_fc, out, tok, t);
        }
    }
}

// Round 3
// 4853.825 us; speedup vs baseline: 2.2847x; 1.0812x over previous
//
#include <hip/hip_runtime.h>
#include <math.h>

#define B 512
#define S 64
#define T 32
#define E 512
#define H 1024
#define VOUTD 128
#define H2 (2*H)
#define H3 (3*H)
#define H6 (6*H)

typedef unsigned short ushortT;
typedef unsigned int uintT;
typedef __attribute__((ext_vector_type(8))) short short8;
typedef __attribute__((ext_vector_type(4))) float floatx4;

__device__ __forceinline__ float sigmoidf_(float x) { return 1.0f / (1.0f + expf(-x)); }

__device__ __forceinline__ uintT pack_hi2(float a, float b) {
    return (__float_as_uint(a) >> 16) | (__float_as_uint(b) & 0xFFFF0000u);
}
__device__ __forceinline__ uintT pack_lo2(float a, float b) {
    uintT ua = __float_as_uint(a), ub = __float_as_uint(b);
    uintT la = __float_as_uint(a - __uint_as_float(ua & 0xFFFF0000u)) >> 16;
    uintT lb = __float_as_uint(b - __uint_as_float(ub & 0xFFFF0000u)) >> 16;
    return la | (lb << 16);
}

__global__ __launch_bounds__(256) void zero16(uint4* __restrict__ p, int n)
{
    int i = blockIdx.x * 256 + threadIdx.x;
    if (i < n) p[i] = make_uint4(0u, 0u, 0u, 0u);
}

// ===========================================================================
// W -> fragment-major hi/lo planes.
// Fragment (jb, c, g, p) = 512 shorts at (((jb*ncK + c)*3 + g)*2 + p)*512.
// Within: lane = (j&15) + 16*((k>>3)&3), elem = k&7 (16x16x32 B-frag layout).
// Thread per (wrow, k8): coalesced 32B read, two 16B frag-slot writes.
// ===========================================================================
__global__ __launch_bounds__(256) void swizzle_w(
    const float* __restrict__ W, ushortT* __restrict__ out, int njShift, int kShift)
{
    int idx = blockIdx.x * 256 + threadIdx.x;
    int total = 3 << (njShift + kShift);
    if (idx >= total) return;
    int wrow = idx >> kShift;
    int k8 = idx & ((1 << kShift) - 1);
    int k = k8 << 3;
    int K = 8 << kShift;
    const float* s = W + (size_t)wrow * K + k;
    float4 f0 = *(const float4*)s;
    float4 f1 = *(const float4*)(s + 4);
    int g = wrow >> njShift;
    int j = wrow & ((1 << njShift) - 1);
    int jb = j >> 4, jl = j & 15;
    int c = k >> 5, kq = (k >> 3) & 3;
    int laneA = jl + 16 * kq;
    int ncK = K >> 5;
    size_t base = (((size_t)(jb * ncK + c) * 3 + g) * 2) * 512 + (size_t)laneA * 8;
    uint4 hv = make_uint4(pack_hi2(f0.x, f0.y), pack_hi2(f0.z, f0.w),
                          pack_hi2(f1.x, f1.y), pack_hi2(f1.z, f1.w));
    uint4 lv = make_uint4(pack_lo2(f0.x, f0.y), pack_lo2(f0.z, f0.w),
                          pack_lo2(f1.x, f1.y), pack_lo2(f1.z, f1.w));
    *(uint4*)(out + base) = hv;
    *(uint4*)(out + base + 512) = lv;
}

// ===========================================================================
// FUSED encoder step. A (h planes) fragment-major in global, read direct to
// registers (L2-resident, coalesced b128 per fragment). B (W planes) fragment-
// major in global, staged 2 chunks at a time into LDS (conflict-free b128
// writes/reads), single barrier per 2 chunks. Gate fused in epilogue; h fp32
// row-major + h planes fragment-major (next step's A) written directly.
// Block: 64 rows x 32 j (96 gate-cols), 4 waves 2x2; wave = 32r x 16j x 3g.
// ===========================================================================
__global__ __launch_bounds__(256) void fused_step_enc(
    const ushortT* __restrict__ Afr,
    const ushortT* __restrict__ WfrF, const ushortT* __restrict__ WfrB,
    const float* __restrict__ giTabF, const float* __restrict__ giTabB,
    const int* __restrict__ src, int s,
    const float* __restrict__ bhF, const float* __restrict__ bhB,
    float* __restrict__ h, ushortT* __restrict__ AfrOut)
{
    __shared__ ushortT sB[2][24 * 512];
    __shared__ int sTok[64];
    const int t = threadIdx.x, lane = t & 63, w = t >> 6;
    const int bid = blockIdx.x;
    const int xcd = bid & 7, q = bid >> 3;
    const int jg = xcd + 8 * (q & 3);     // [0,32)
    const int mb = q >> 2;                // [0,16)
    const int j0 = jg * 32, m0 = mb * 64;
    const bool bwd = (m0 >= B);
    const ushortT* Wfr = bwd ? WfrB : WfrF;
    const float* giTab = bwd ? giTabB : giTabF;
    const float* bh = bwd ? bhB : bhF;
    const int NCK = 32, NIT = 16;

    if (t < 64) {
        int b = (m0 + t) & (B - 1);
        sTok[t] = src[b * S + (bwd ? (S - 1 - s) : s)];
    }

    const int wr = w >> 1, wc = w & 1;
    const ushortT* aP = Afr + (size_t)((m0 >> 4) + wr * 2) * (NCK * 1024) + lane * 8;

    const ushortT* gWb[3];
    int lds0[3], lds1[3];
#pragma unroll
    for (int k = 0; k < 3; ++k) {
        int f = w * 3 + k;
        int jbLoc = f / 6, rem = f % 6;
        gWb[k] = Wfr + (size_t)(jg * 2 + jbLoc) * (NCK * 3072) + rem * 512 + lane * 8;
        lds0[k] = f * 512 + lane * 8;
        lds1[k] = (12 + f) * 512 + lane * 8;
    }
    const int rb0 = wc * 3072 + lane * 8;     // B read base; + g*1024 + p*512

    floatx4 acc[2][3];
#pragma unroll
    for (int mi = 0; mi < 2; ++mi)
#pragma unroll
        for (int g = 0; g < 3; ++g) acc[mi][g] = (floatx4){0.f, 0.f, 0.f, 0.f};

    uint4 st0[3], st1[3];
#pragma unroll
    for (int k = 0; k < 3; ++k) {
        st0[k] = *(const uint4*)(gWb[k]);
        st1[k] = *(const uint4*)(gWb[k] + 3072);
    }
#pragma unroll
    for (int k = 0; k < 3; ++k) {
        *(uint4*)&sB[0][lds0[k]] = st0[k];
        *(uint4*)&sB[0][lds1[k]] = st1[k];
    }
    __syncthreads();

    short8 an00 = *(const short8*)(aP);
    short8 an01 = *(const short8*)(aP + 512);
    short8 an10 = *(const short8*)(aP + NCK * 1024);
    short8 an11 = *(const short8*)(aP + NCK * 1024 + 512);

    int pb = 0;
    for (int it = 0; it < NIT; ++it) {
        if (it + 1 < NIT) {
            int cb = (it + 1) * 2;
#pragma unroll
            for (int k = 0; k < 3; ++k) {
                st0[k] = *(const uint4*)(gWb[k] + (size_t)cb * 3072);
                st1[k] = *(const uint4*)(gWb[k] + (size_t)(cb + 1) * 3072);
            }
        }
        const ushortT* bp = &sB[pb][0];
        // ---- sub-chunk 0 (c = 2*it)
        {
            short8 a00 = an00, a01 = an01, a10 = an10, a11 = an11;
            int cn = 2 * it + 1;
            an00 = *(const short8*)(aP + (size_t)cn * 1024);
            an01 = *(const short8*)(aP + (size_t)cn * 1024 + 512);
            an10 = *(const short8*)(aP + (size_t)cn * 1024 + NCK * 1024);
            an11 = *(const short8*)(aP + (size_t)cn * 1024 + NCK * 1024 + 512);
#pragma unroll
            for (int g = 0; g < 3; ++g) {
                short8 bhf = *(const short8*)&bp[rb0 + g * 1024];
                short8 blf = *(const short8*)&bp[rb0 + g * 1024 + 512];
                acc[0][g] = __builtin_amdgcn_mfma_f32_16x16x32_bf16(a00, bhf, acc[0][g], 0, 0, 0);
                acc[0][g] = __builtin_amdgcn_mfma_f32_16x16x32_bf16(a00, blf, acc[0][g], 0, 0, 0);
                acc[0][g] = __builtin_amdgcn_mfma_f32_16x16x32_bf16(a01, bhf, acc[0][g], 0, 0, 0);
                acc[1][g] = __builtin_amdgcn_mfma_f32_16x16x32_bf16(a10, bhf, acc[1][g], 0, 0, 0);
                acc[1][g] = __builtin_amdgcn_mfma_f32_16x16x32_bf16(a10, blf, acc[1][g], 0, 0, 0);
                acc[1][g] = __builtin_amdgcn_mfma_f32_16x16x32_bf16(a11, bhf, acc[1][g], 0, 0, 0);
            }
        }
        // ---- sub-chunk 1 (c = 2*it+1)
        {
            short8 a00 = an00, a01 = an01, a10 = an10, a11 = an11;
            int cn = 2 * it + 2; if (cn >= NCK) cn = NCK - 1;
            an00 = *(const short8*)(aP + (size_t)cn * 1024);
            an01 = *(const short8*)(aP + (size_t)cn * 1024 + 512);
            an10 = *(const short8*)(aP + (size_t)cn * 1024 + NCK * 1024);
            an11 = *(const short8*)(aP + (size_t)cn * 1024 + NCK * 1024 + 512);
#pragma unroll
            for (int g = 0; g < 3; ++g) {
                short8 bhf = *(const short8*)&bp[12 * 512 + rb0 + g * 1024];
                short8 blf = *(const short8*)&bp[12 * 512 + rb0 + g * 1024 + 512];
                acc[0][g] = __builtin_amdgcn_mfma_f32_16x16x32_bf16(a00, bhf, acc[0][g], 0, 0, 0);
                acc[0][g] = __builtin_amdgcn_mfma_f32_16x16x32_bf16(a00, blf, acc[0][g], 0, 0, 0);
                acc[0][g] = __builtin_amdgcn_mfma_f32_16x16x32_bf16(a01, bhf, acc[0][g], 0, 0, 0);
                acc[1][g] = __builtin_amdgcn_mfma_f32_16x16x32_bf16(a10, bhf, acc[1][g], 0, 0, 0);
                acc[1][g] = __builtin_amdgcn_mfma_f32_16x16x32_bf16(a10, blf, acc[1][g], 0, 0, 0);
                acc[1][g] = __builtin_amdgcn_mfma_f32_16x16x32_bf16(a11, bhf, acc[1][g], 0, 0, 0);
            }
        }
        if (it + 1 < NIT) {
#pragma unroll
            for (int k = 0; k < 3; ++k) {
                *(uint4*)&sB[pb ^ 1][lds0[k]] = st0[k];
                *(uint4*)&sB[pb ^ 1][lds1[k]] = st1[k];
            }
            __syncthreads();
            pb ^= 1;
        }
    }

    // fused gate epilogue
    const int colj = j0 + wc * 16 + (lane & 15);
    const float bR = bh[colj], bZ = bh[H + colj], bN = bh[2 * H + colj];
    const int rloc0 = wr * 32 + (lane >> 4) * 4;
    const int cA = colj >> 5;
    const int kqA = (colj >> 3) & 3;
    const int eA = colj & 7;
#pragma unroll
    for (int mi = 0; mi < 2; ++mi) {
#pragma unroll
        for (int r = 0; r < 4; ++r) {
            const int rloc = rloc0 + mi * 16 + r;
            const int row = m0 + rloc;
            const float* gi = giTab + (size_t)sTok[rloc] * H3;
            float ghr = acc[mi][0][r] + bR;
            float ghz = acc[mi][1][r] + bZ;
            float ghn = acc[mi][2][r] + bN;
            float rr = sigmoidf_(gi[colj] + ghr);
            float z  = sigmoidf_(gi[H + colj] + ghz);
            float n  = tanhf(gi[2 * H + colj] + rr * ghn);
            const size_t idx = (size_t)row * H + colj;
            float hnew = (1.0f - z) * n + z * h[idx];
            h[idx] = hnew;
            uintT u = __float_as_uint(hnew);
            size_t ao = (((size_t)(row >> 4) * 32 + cA) * 2) * 512
                      + (size_t)((row & 15) + 16 * kqA) * 8 + eA;
            AfrOut[ao] = (ushortT)(u >> 16);
            AfrOut[ao + 512] = (ushortT)(__float_as_uint(hnew - __uint_as_float(u & 0xFFFF0000u)) >> 16);
        }
    }
}

// ===========================================================================
// FUSED decoder step: Hd = 2H, gates at {j, 2H+j, 4H+j}. Same structure.
// Block: 64 rows x 32 j; grid 512 = 8 mb x 64 jg.
// ===========================================================================
__global__ __launch_bounds__(256) void fused_step_dec(
    const ushortT* __restrict__ Afr, const ushortT* __restrict__ Wfr,
    const float* __restrict__ giTabD, const int* __restrict__ tok,
    const float* __restrict__ bhD,
    float* __restrict__ h, ushortT* __restrict__ AfrOut)
{
    __shared__ ushortT sB[2][24 * 512];
    __shared__ int sTok[64];
    const int t = threadIdx.x, lane = t & 63, w = t >> 6;
    const int bid = blockIdx.x;
    const int xcd = bid & 7, q = bid >> 3;
    const int jg = xcd + 8 * (q & 7);     // [0,64)
    const int mb = q >> 3;                // [0,8)
    const int j0 = jg * 32, m0 = mb * 64;
    const int NCK = 64, NIT = 32;

    if (t < 64) sTok[t] = tok[m0 + t];

    const int wr = w >> 1, wc = w & 1;
    const ushortT* aP = Afr + (size_t)((m0 >> 4) + wr * 2) * (NCK * 1024) + lane * 8;

    const ushortT* gWb[3];
    int lds0[3], lds1[3];
#pragma unroll
    for (int k = 0; k < 3; ++k) {
        int f = w * 3 + k;
        int jbLoc = f / 6, rem = f % 6;
        gWb[k] = Wfr + (size_t)(jg * 2 + jbLoc) * (NCK * 3072) + rem * 512 + lane * 8;
        lds0[k] = f * 512 + lane * 8;
        lds1[k] = (12 + f) * 512 + lane * 8;
    }
    const int rb0 = wc * 3072 + lane * 8;

    floatx4 acc[2][3];
#pragma unroll
    for (int mi = 0; mi < 2; ++mi)
#pragma unroll
        for (int g = 0; g < 3; ++g) acc[mi][g] = (floatx4){0.f, 0.f, 0.f, 0.f};

    uint4 st0[3], st1[3];
#pragma unroll
    for (int k = 0; k < 3; ++k) {
        st0[k] = *(const uint4*)(gWb[k]);
        st1[k] = *(const uint4*)(gWb[k] + 3072);
    }
#pragma unroll
    for (int k = 0; k < 3; ++k) {
        *(uint4*)&sB[0][lds0[k]] = st0[k];
        *(uint4*)&sB[0][lds1[k]] = st1[k];
    }
    __syncthreads();

    short8 an00 = *(const short8*)(aP);
    short8 an01 = *(const short8*)(aP + 512);
    short8 an10 = *(const short8*)(aP + NCK * 1024);
    short8 an11 = *(const short8*)(aP + NCK * 1024 + 512);

    int pb = 0;
    for (int it = 0; it < NIT; ++it) {
        if (it + 1 < NIT) {
            int cb = (it + 1) * 2;
#pragma unroll
            for (int k = 0; k < 3; ++k) {
                st0[k] = *(const uint4*)(gWb[k] + (size_t)cb * 3072);
                st1[k] = *(const uint4*)(gWb[k] + (size_t)(cb + 1) * 3072);
            }
        }
        const ushortT* bp = &sB[pb][0];
        {
            short8 a00 = an00, a01 = an01, a10 = an10, a11 = an11;
            int cn = 2 * it + 1;
            an00 = *(const short8*)(aP + (size_t)cn * 1024);
            an01 = *(const short8*)(aP + (size_t)cn * 1024 + 512);
            an10 = *(const short8*)(aP + (size_t)cn * 1024 + NCK * 1024);
            an11 = *(const short8*)(aP + (size_t)cn * 1024 + NCK * 1024 + 512);
#pragma unroll
            for (int g = 0; g < 3; ++g) {
                short8 bhf = *(const short8*)&bp[rb0 + g * 1024];
                short8 blf = *(const short8*)&bp[rb0 + g * 1024 + 512];
                acc[0][g] = __builtin_amdgcn_mfma_f32_16x16x32_bf16(a00, bhf, acc[0][g], 0, 0, 0);
                acc[0][g] = __builtin_amdgcn_mfma_f32_16x16x32_bf16(a00, blf, acc[0][g], 0, 0, 0);
                acc[0][g] = __builtin_amdgcn_mfma_f32_16x16x32_bf16(a01, bhf, acc[0][g], 0, 0, 0);
                acc[1][g] = __builtin_amdgcn_mfma_f32_16x16x32_bf16(a10, bhf, acc[1][g], 0, 0, 0);
                acc[1][g] = __builtin_amdgcn_mfma_f32_16x16x32_bf16(a10, blf, acc[1][g], 0, 0, 0);
                acc[1][g] = __builtin_amdgcn_mfma_f32_16x16x32_bf16(a11, bhf, acc[1][g], 0, 0, 0);
            }
        }
        {
            short8 a00 = an00, a01 = an01, a10 = an10, a11 = an11;
            int cn = 2 * it + 2; if (cn >= NCK) cn = NCK - 1;
            an00 = *(const short8*)(aP + (size_t)cn * 1024);
            an01 = *(const short8*)(aP + (size_t)cn * 1024 + 512);
            an10 = *(const short8*)(aP + (size_t)cn * 1024 + NCK * 1024);
            an11 = *(const short8*)(aP + (size_t)cn * 1024 + NCK * 1024 + 512);
#pragma unroll
            for (int g = 0; g < 3; ++g) {
                short8 bhf = *(const short8*)&bp[12 * 512 + rb0 + g * 1024];
                short8 blf = *(const short8*)&bp[12 * 512 + rb0 + g * 1024 + 512];
                acc[0][g] = __builtin_amdgcn_mfma_f32_16x16x32_bf16(a00, bhf, acc[0][g], 0, 0, 0);
                acc[0][g] = __builtin_amdgcn_mfma_f32_16x16x32_bf16(a00, blf, acc[0][g], 0, 0, 0);
                acc[0][g] = __builtin_amdgcn_mfma_f32_16x16x32_bf16(a01, bhf, acc[0][g], 0, 0, 0);
                acc[1][g] = __builtin_amdgcn_mfma_f32_16x16x32_bf16(a10, bhf, acc[1][g], 0, 0, 0);
                acc[1][g] = __builtin_amdgcn_mfma_f32_16x16x32_bf16(a10, blf, acc[1][g], 0, 0, 0);
                acc[1][g] = __builtin_amdgcn_mfma_f32_16x16x32_bf16(a11, bhf, acc[1][g], 0, 0, 0);
            }
        }
        if (it + 1 < NIT) {
#pragma unroll
            for (int k = 0; k < 3; ++k) {
                *(uint4*)&sB[pb ^ 1][lds0[k]] = st0[k];
                *(uint4*)&sB[pb ^ 1][lds1[k]] = st1[k];
            }
            __syncthreads();
            pb ^= 1;
        }
    }

    const int colj = j0 + wc * 16 + (lane & 15);
    const float bR = bhD[colj], bZ = bhD[H2 + colj], bN = bhD[2 * H2 + colj];
    const int rloc0 = wr * 32 + (lane >> 4) * 4;
    const int cA = colj >> 5;
    const int kqA = (colj >> 3) & 3;
    const int eA = colj & 7;
#pragma unroll
    for (int mi = 0; mi < 2; ++mi) {
#pragma unroll
        for (int r = 0; r < 4; ++r) {
            const int rloc = rloc0 + mi * 16 + r;
            const int row = m0 + rloc;
            const float* gi = giTabD + (size_t)sTok[rloc] * H6;
            float ghr = acc[mi][0][r] + bR;
            float ghz = acc[mi][1][r] + bZ;
            float ghn = acc[mi][2][r] + bN;
            float rr = sigmoidf_(gi[colj] + ghr);
            float z  = sigmoidf_(gi[H2 + colj] + ghz);
            float n  = tanhf(gi[2 * H2 + colj] + rr * ghn);
            const size_t idx = (size_t)row * H2 + colj;
            float hnew = (1.0f - z) * n + z * h[idx];
            h[idx] = hnew;
            uintT u = __float_as_uint(hnew);
            size_t ao = (((size_t)(row >> 4) * 64 + cA) * 2) * 512
                      + (size_t)((row & 15) + 16 * kqA) * 8 + eA;
            AfrOut[ao] = (ushortT)(u >> 16);
            AfrOut[ao + 512] = (ushortT)(__float_as_uint(hnew - __uint_as_float(u & 0xFFFF0000u)) >> 16);
        }
    }
}

// hh fp32 row-major + dec A planes (fragment-major); tok[b]=tgt[b,0]
__global__ __launch_bounds__(256) void init_hh_tok_split(
    const float* __restrict__ h_f, const float* __restrict__ h_b,
    const int* __restrict__ tgt, float* __restrict__ hh,
    ushortT* __restrict__ AfrD, int* __restrict__ tok)
{
    int i = blockIdx.x * blockDim.x + threadIdx.x;   // over B*2H
    int b = i >> 11;
    int j = i & 2047;
    float v = (j < H) ? h_f[(size_t)b * H + j] : h_b[(size_t)b * H + (j - H)];
    hh[i] = v;
    uintT u = __float_as_uint(v);
    size_t ao = (((size_t)(b >> 4) * 64 + (j >> 5)) * 2) * 512
              + (size_t)((b & 15) + 16 * ((j >> 3) & 3)) * 8 + (j & 7);
    AfrD[ao] = (ushortT)(u >> 16);
    AfrD[ao + 512] = (ushortT)(__float_as_uint(v - __uint_as_float(u & 0xFFFF0000u)) >> 16);
    if (j == 0) tok[b] = tgt[b * T];
}

// ===========================================================================
// logits = hh @ W_fc^T + b_fc (V=128) + argmax; 2 rows/block, 256 thr.
// ===========================================================================
__global__ __launch_bounds__(256) void logits_argmax2(
    const float* __restrict__ hh, const float* __restrict__ W_fc,
    const float* __restrict__ b_fc, float* __restrict__ out,
    int* __restrict__ tok, int t)
{
    __shared__ float sh[2][H2];
    __shared__ float sred[2][2][128];
    __shared__ float sval[2][128];
    __shared__ int   sidx[2][128];
    const int tid = threadIdx.x;
    const int col = tid & 127;
    const int kh  = tid >> 7;
    const int b0  = blockIdx.x * 2;

    {
        const float4* srcp = (const float4*)(hh + (size_t)b0 * H2);
        float4* dst = (float4*)sh;
        for (int i = tid; i < 2 * H2 / 4; i += 256) dst[i] = srcp[i];
    }
    __syncthreads();

    const float* wrow = W_fc + (size_t)col * H2 + kh * (H2 / 2);
    const float* s0 = sh[0] + kh * (H2 / 2);
    const float* s1 = sh[1] + kh * (H2 / 2);
    float a0 = 0.f, a1 = 0.f;
#pragma unroll 8
    for (int k = 0; k < H2 / 2; k += 4) {
        float4 w4 = *(const float4*)(wrow + k);
        float4 h0 = *(const float4*)(s0 + k);
        float4 h1 = *(const float4*)(s1 + k);
        a0 += w4.x * h0.x + w4.y * h0.y + w4.z * h0.z + w4.w * h0.w;
        a1 += w4.x * h1.x + w4.y * h1.y + w4.z * h1.z + w4.w * h1.w;
    }
    sred[kh][0][col] = a0;
    sred[kh][1][col] = a1;
    __syncthreads();

    if (kh == 0) {
        float l0 = sred[0][0][col] + sred[1][0][col] + b_fc[col];
        float l1 = sred[0][1][col] + sred[1][1][col] + b_fc[col];
        out[(size_t)(b0 + 0) * ((T - 1) * VOUTD) + (size_t)t * VOUTD + col] = l0;
        out[(size_t)(b0 + 1) * ((T - 1) * VOUTD) + (size_t)t * VOUTD + col] = l1;
        sval[0][col] = l0; sidx[0][col] = col;
        sval[1][col] = l1; sidx[1][col] = col;
    }
    __syncthreads();

    const int r = tid >> 7, c = tid & 127;
    for (int off = 64; off > 0; off >>= 1) {
        if (c < off) {
            float ov = sval[r][c + off]; int oi = sidx[r][c + off];
            if (ov > sval[r][c] || (ov == sval[r][c] && oi < sidx[r][c])) {
                sval[r][c] = ov; sidx[r][c] = oi;
            }
        }
        __syncthreads();
    }
    if (tid < 2) tok[b0 + tid] = sidx[tid][0];
}

// ===========================================================================
// fp32 vector GEMM (R1-proven): gi-table precompute + fallback path.
// ===========================================================================
__global__ __launch_bounds__(256) void gemm_bias(
    const float* __restrict__ Abase,
    const int* __restrict__ idx, int idxStride, int idxOff, int lda,
    const float* __restrict__ W, const float* __restrict__ bias,
    float* __restrict__ C, int N, int K)
{
    __shared__ float As[16][68];
    __shared__ float Ws[16][68];
    const int t = threadIdx.x;
    const int m0 = blockIdx.y * 64, n0 = blockIdx.x * 64;
    const int lr = t >> 2, lc = (t & 3) << 2;
    const int tx = t & 15, ty = t >> 4;
    const int tn0 = tx << 2, tm0 = ty << 2;
    const int arow = m0 + lr;
    const float* Aptr = idx ? (Abase + (size_t)idx[arow * idxStride + idxOff] * lda)
                            : (Abase + (size_t)arow * lda);
    const float* Wptr = W + (size_t)(n0 + lr) * K;
    float acc[4][4] = {{0.f}};
    for (int k0 = 0; k0 < K; k0 += 16) {
        float4 a4 = *(const float4*)(Aptr + k0 + lc);
        float4 w4 = *(const float4*)(Wptr + k0 + lc);
        __syncthreads();
        As[lc+0][lr] = a4.x; As[lc+1][lr] = a4.y; As[lc+2][lr] = a4.z; As[lc+3][lr] = a4.w;
        Ws[lc+0][lr] = w4.x; Ws[lc+1][lr] = w4.y; Ws[lc+2][lr] = w4.z; Ws[lc+3][lr] = w4.w;
        __syncthreads();
#pragma unroll
        for (int kk = 0; kk < 16; ++kk) {
            float4 av = *(const float4*)&As[kk][tm0];
            float4 wv = *(const float4*)&Ws[kk][tn0];
            float am[4] = {av.x, av.y, av.z, av.w};
            float wn[4] = {wv.x, wv.y, wv.z, wv.w};
#pragma unroll
            for (int i = 0; i < 4; ++i)
#pragma unroll
                for (int j = 0; j < 4; ++j) acc[i][j] += am[i] * wn[j];
        }
    }
    const float b0 = bias[n0+tn0], b1 = bias[n0+tn0+1], b2 = bias[n0+tn0+2], b3 = bias[n0+tn0+3];
#pragma unroll
    for (int i = 0; i < 4; ++i) {
        float4 o = make_float4(acc[i][0]+b0, acc[i][1]+b1, acc[i][2]+b2, acc[i][3]+b3);
        *(float4*)(C + (size_t)(m0 + tm0 + i) * N + n0 + tn0) = o;
    }
}

__global__ __launch_bounds__(256) void gemm_enc(
    const float* __restrict__ Abase, int lda, int K,
    const int* __restrict__ srcIdx, int s,
    const float* __restrict__ W1, const float* __restrict__ bias1,
    const float* __restrict__ W2, const float* __restrict__ bias2,
    float* __restrict__ C, int N)
{
    __shared__ float As[16][68];
    __shared__ float Ws[16][68];
    const int t = threadIdx.x;
    const int m0 = blockIdx.y * 64, n0 = blockIdx.x * 64;
    const bool bwd = (m0 >= B);
    const float* W = bwd ? W2 : W1;
    const float* bias = bwd ? bias2 : bias1;
    const int lr = t >> 2, lc = (t & 3) << 2;
    const int tx = t & 15, ty = t >> 4;
    const int tn0 = tx << 2, tm0 = ty << 2;
    const int arow = m0 + lr;
    const float* Aptr;
    if (srcIdx) {
        int r = arow & (B - 1);
        int sidx = bwd ? (S - 1 - s) : s;
        Aptr = Abase + (size_t)srcIdx[r * S + sidx] * lda;
    } else Aptr = Abase + (size_t)arow * lda;
    const float* Wptr = W + (size_t)(n0 + lr) * K;
    float acc[4][4] = {{0.f}};
    for (int k0 = 0; k0 < K; k0 += 16) {
        float4 a4 = *(const float4*)(Aptr + k0 + lc);
        float4 w4 = *(const float4*)(Wptr + k0 + lc);
        __syncthreads();
        As[lc+0][lr] = a4.x; As[lc+1][lr] = a4.y; As[lc+2][lr] = a4.z; As[lc+3][lr] = a4.w;
        Ws[lc+0][lr] = w4.x; Ws[lc+1][lr] = w4.y; Ws[lc+2][lr] = w4.z; Ws[lc+3][lr] = w4.w;
        __syncthreads();
#pragma unroll
        for (int kk = 0; kk < 16; ++kk) {
            float4 av = *(const float4*)&As[kk][tm0];
            float4 wv = *(const float4*)&Ws[kk][tn0];
            float am[4] = {av.x, av.y, av.z, av.w};
            float wn[4] = {wv.x, wv.y, wv.z, wv.w};
#pragma unroll
            for (int i = 0; i < 4; ++i)
#pragma unroll
                for (int j = 0; j < 4; ++j) acc[i][j] += am[i] * wn[j];
        }
    }
    const float b0 = bias[n0+tn0], b1 = bias[n0+tn0+1], b2 = bias[n0+tn0+2], b3 = bias[n0+tn0+3];
#pragma unroll
    for (int i = 0; i < 4; ++i) {
        float4 o = make_float4(acc[i][0]+b0, acc[i][1]+b1, acc[i][2]+b2, acc[i][3]+b3);
        *(float4*)(C + (size_t)(m0 + tm0 + i) * N + n0 + tn0) = o;
    }
}

__global__ __launch_bounds__(256) void gru_gate(
    const float* __restrict__ gi, const float* __restrict__ gh,
    float* __restrict__ h, int Hd)
{
    int i = blockIdx.x * blockDim.x + threadIdx.x;
    int b = i / Hd, j = i - b * Hd;
    const float* gib = gi + (size_t)b * 3 * Hd;
    const float* ghb = gh + (size_t)b * 3 * Hd;
    float r = sigmoidf_(gib[j] + ghb[j]);
    float z = sigmoidf_(gib[Hd + j] + ghb[Hd + j]);
    float n = tanhf(gib[2 * Hd + j] + r * ghb[2 * Hd + j]);
    h[i] = (1.0f - z) * n + z * h[i];
}

__global__ __launch_bounds__(256) void init_hh_tok(
    const float* __restrict__ h_f, const float* __restrict__ h_b,
    const int* __restrict__ tgt, float* __restrict__ hh, int* __restrict__ tok)
{
    int i = blockIdx.x * blockDim.x + threadIdx.x;
    int b = i >> 11, j = i & 2047;
    hh[i] = (j < H) ? h_f[(size_t)b * H + j] : h_b[(size_t)b * H + (j - H)];
    if (j == 0) tok[b] = tgt[b * T];
}

// ===========================================================================
extern "C" void kernel_launch(void* const* d_in, const int* in_sizes, int n_in,
                              void* d_out, int out_size, void* d_ws, size_t ws_size,
                              hipStream_t stream)
{
    const int*   src     = (const int*)d_in[0];
    const int*   tgt     = (const int*)d_in[1];
    const float* enc_emb = (const float*)d_in[2];
    const float* dec_emb = (const float*)d_in[3];
    const float* W_ih_f  = (const float*)d_in[4];
    const float* W_hh_f  = (const float*)d_in[5];
    const float* b_ih_f  = (const float*)d_in[6];
    const float* b_hh_f  = (const float*)d_in[7];
    const float* W_ih_b  = (const float*)d_in[8];
    const float* W_hh_b  = (const float*)d_in[9];
    const float* b_ih_b  = (const float*)d_in[10];
    const float* b_hh_b  = (const float*)d_in[11];
    const float* W_ih_d  = (const float*)d_in[12];
    const float* W_hh_d  = (const float*)d_in[13];
    const float* b_ih_d  = (const float*)d_in[14];
    const float* b_hh_d  = (const float*)d_in[15];
    const float* W_fc    = (const float*)d_in[16];
    const float* b_fc    = (const float*)d_in[17];
    float* out = (float*)d_out;

    // ---------------- workspace layout ----------------
    char* base = (char*)d_ws;
    size_t off = 0;
    auto alloc = [&](size_t bytes) { char* p = base + off; off += (bytes + 255) & ~(size_t)255; return p; };

    float*   hE     = (float*)  alloc((size_t)2 * B * H * 4);       // 8 MB (zeroed with AfrEA)
    ushortT* AfrEA  = (ushortT*)alloc((size_t)2 * B * H * 2 * 2);   // enc A planes ping (4.2 MB)
    ushortT* AfrEB  = (ushortT*)alloc((size_t)2 * B * H * 2 * 2);   // enc A planes pong
    float*   hh     = (float*)  alloc((size_t)B * H2 * 4);
    ushortT* AfrDA  = (ushortT*)alloc((size_t)B * H2 * 2 * 2);      // dec A planes ping
    ushortT* AfrDB  = (ushortT*)alloc((size_t)B * H2 * 2 * 2);      // dec A planes pong
    float*   giTabF = (float*)  alloc((size_t)VOUTD * H3 * 4);
    float*   giTabB = (float*)  alloc((size_t)VOUTD * H3 * 4);
    float*   giTabD = (float*)  alloc((size_t)VOUTD * H6 * 4);
    ushortT* WfrF   = (ushortT*)alloc((size_t)H3 * H * 2 * 2);      // 12.6 MB
    ushortT* WfrB   = (ushortT*)alloc((size_t)H3 * H * 2 * 2);
    ushortT* WfrD   = (ushortT*)alloc((size_t)H6 * H2 * 2 * 2);     // 50.3 MB
    int*     tok    = (int*)    alloc((size_t)B * 4);
    size_t required = off;

    dim3 blk(256);

    if (ws_size >= required) {
        // =================== fragment-major fused path ===================
        {   // zero hE fp32 + AfrEA (contiguous)
            size_t zbytes = (size_t)2 * B * H * 4 + (size_t)2 * B * H * 4;
            int n16 = (int)(zbytes / 16);
            zero16<<<dim3((n16 + 255) / 256), blk, 0, stream>>>((uint4*)hE, n16);
        }
        // W -> fragment-major hi/lo
        swizzle_w<<<dim3((3 * H3 * H / (3 * 8) * 3 / 256) ? ((3 << 17) + 255) / 256 : 1), blk, 0, stream>>>(
            W_hh_f, WfrF, 10, 7);
        swizzle_w<<<dim3(((3 << 17) + 255) / 256), blk, 0, stream>>>(W_hh_b, WfrB, 10, 7);
        swizzle_w<<<dim3(((3 << 19) + 255) / 256), blk, 0, stream>>>(W_hh_d, WfrD, 11, 8);

        // gi tables (exact fp32)
        gemm_bias<<<dim3(H3 / 64, VOUTD / 64), blk, 0, stream>>>(
            enc_emb, nullptr, 0, 0, E, W_ih_f, b_ih_f, giTabF, H3, E);
        gemm_bias<<<dim3(H3 / 64, VOUTD / 64), blk, 0, stream>>>(
            enc_emb, nullptr, 0, 0, E, W_ih_b, b_ih_b, giTabB, H3, E);
        gemm_bias<<<dim3(H6 / 64, VOUTD / 64), blk, 0, stream>>>(
            dec_emb, nullptr, 0, 0, E, W_ih_d, b_ih_d, giTabD, H6, E);

        // ---------------- Encoder: 64 fused steps ----------------
        for (int s = 0; s < S; ++s) {
            const ushortT* inA = (s & 1) ? AfrEB : AfrEA;
            ushortT* outA = (s & 1) ? AfrEA : AfrEB;
            fused_step_enc<<<dim3(512), blk, 0, stream>>>(
                inA, WfrF, WfrB, giTabF, giTabB, src, s, b_hh_f, b_hh_b, hE, outA);
        }

        init_hh_tok_split<<<dim3((B * H2) / 256), blk, 0, stream>>>(
            hE, hE + (size_t)B * H, tgt, hh, AfrDA, tok);

        // ---------------- Decoder: 31 fused steps ----------------
        for (int t = 0; t < T - 1; ++t) {
            const ushortT* inA = (t & 1) ? AfrDB : AfrDA;
            ushortT* outA = (t & 1) ? AfrDA : AfrDB;
            fused_step_dec<<<dim3(512), blk, 0, stream>>>(
                inA, WfrD, giTabD, tok, b_hh_d, hh, outA);
            logits_argmax2<<<dim3(B / 2), blk, 0, stream>>>(hh, W_fc, b_fc, out, tok, t);
        }
    } else {
        // =================== fp32 fallback (R1-proven path) ===================
        {
            size_t zbytes = (size_t)2 * B * H * 4;
            int n16 = (int)(zbytes / 16);
            zero16<<<dim3((n16 + 255) / 256), blk, 0, stream>>>((uint4*)hE, n16);
        }
        float* giE = (float*)WfrF;                       // scratch overlay (75 MB region)
        float* ghF = giE + (size_t)2 * B * H3;
        dim3 grid_gi(H3 / 64, (2 * B) / 64);
        dim3 grid_gate((2 * B * H) / 256);
        for (int s = 0; s < S; ++s) {
            gemm_enc<<<grid_gi, blk, 0, stream>>>(enc_emb, E, E, src, s,
                                                  W_ih_f, b_ih_f, W_ih_b, b_ih_b, giE, H3);
            gemm_enc<<<grid_gi, blk, 0, stream>>>(hE, H, H, nullptr, 0,
                                                  W_hh_f, b_hh_f, W_hh_b, b_hh_b, ghF, H3);
            gru_gate<<<grid_gate, blk, 0, stream>>>(giE, ghF, hE, H);
        }
        init_hh_tok<<<dim3((B * H2) / 256), blk, 0, stream>>>(hE, hE + (size_t)B * H, tgt, hh, tok);
        dim3 grid_d(H6 / 64, B / 64);
        dim3 grid_dgate((B * H2) / 256);
        for (int t = 0; t < T - 1; ++t) {
            gemm_bias<<<grid_d, blk, 0, stream>>>(dec_emb, tok, 1, 0, E,
                                                  W_ih_d, b_ih_d, giE, H6, E);
            gemm_bias<<<grid_d, blk, 0, stream>>>(hh, nullptr, 0, 0, H2,
                                                  W_hh_d, b_hh_d, ghF, H6, H2);
            gru_gate<<<grid_dgate, blk, 0, stream>>>(giE, ghF, hh, H2);
            logits_argmax2<<<dim3(B / 2), blk, 0, stream>>>(hh, W_fc, b_fc, out, tok, t);
        }
    }
}